// Round 6
// baseline (170.592 us; speedup 1.0000x reference)
//
#include <hip/hip_runtime.h>

typedef unsigned short u16;
typedef unsigned int u32;
typedef __attribute__((ext_vector_type(8))) short sh8;           // 8 bf16 (4 VGPR)
typedef __attribute__((ext_vector_type(8))) unsigned short us8;
typedef __attribute__((ext_vector_type(2))) unsigned int ui2;
typedef __attribute__((ext_vector_type(4))) float f4;

__device__ __forceinline__ float bf2f(u16 u) {
  union { unsigned u; float f; } v; v.u = ((unsigned)u) << 16; return v.f;
}
__device__ __forceinline__ u16 f2bf(float f) {
  union { float f; unsigned u; } v; v.f = f;
  unsigned r = v.u + 0x7fffu + ((v.u >> 16) & 1u);   // RNE, inputs finite
  return (u16)(r >> 16);
}
// async global->LDS, 16B per lane; dest = wave-uniform base + lane*16
__device__ __forceinline__ void gl16(const void* g, void* l) {
  __builtin_amdgcn_global_load_lds(
      (const __attribute__((address_space(1))) unsigned int*)g,
      (__attribute__((address_space(3))) unsigned int*)l, 16, 0, 0);
}

// ---------------- f32 -> bf16, 8 elems/thread ----------------
__global__ __launch_bounds__(256)
void k_cvt_bf16(const float* __restrict__ in, u16* __restrict__ out, int n8) {
  int idx = blockIdx.x * 256 + threadIdx.x;
  if (idx >= n8) return;
  const f4* p = (const f4*)in + (size_t)idx * 2;
  f4 a = p[0], b = p[1];
  us8 o;
  o[0] = f2bf(a[0]); o[1] = f2bf(a[1]); o[2] = f2bf(a[2]); o[3] = f2bf(a[3]);
  o[4] = f2bf(b[0]); o[5] = f2bf(b[1]); o[6] = f2bf(b[2]); o[7] = f2bf(b[3]);
  ((us8*)out)[idx] = o;
}

// ------- weights: concat + transpose to Wt[n][k] bf16, n in [0,6144) -------
__global__ __launch_bounds__(256)
void k_prep_w(const float* __restrict__ Wq, const float* __restrict__ Wl,
              const float* __restrict__ Wc, const float* __restrict__ Wo,
              u16* __restrict__ Wt) {
  __shared__ u16 tile[64][65];
  const int n0 = blockIdx.x * 64;
  const int k0 = blockIdx.y * 64;
  const float* src; int ld, col0;
  if (n0 < 1024)      { src = Wq; ld = 1024; col0 = n0; }
  else if (n0 < 3072) { src = Wl; ld = 2048; col0 = n0 - 1024; }
  else if (n0 < 5120) { src = Wc; ld = 2048; col0 = n0 - 3072; }
  else                { src = Wo; ld = 1024; col0 = n0 - 5120; }
  const int t = threadIdx.x;
  const int r = t >> 2;          // 0..63
  const int c0 = (t & 3) * 16;   // 0,16,32,48
  const float* sp = src + (size_t)(k0 + r) * ld + col0 + c0;
  #pragma unroll
  for (int j = 0; j < 16; j++) tile[r][c0 + j] = f2bf(sp[j]);
  __syncthreads();
  u16* op = Wt + (size_t)(n0 + r) * 1024 + k0 + c0;
  #pragma unroll
  for (int j = 0; j < 16; j++) op[j] = tile[c0 + j][r];
}

// ======== pipelined 256x256 MFMA GEMM (T3+T4+T5), A[M][K] * Bt[N][K]^T ========
// BK=32, 3-slot LDS rotation (stage kt+2 while reading kt; slot last read kt-1),
// 8 waves (2M x 4N), per-wave 128x64, counted vmcnt(5) gate once per K-tile.
// LDS rows padded to 40 u16 (80B) -> frag-read bank stride 20 -> 2-way (free).
__global__ __launch_bounds__(512)
void k_gemm8(const u16* __restrict__ A, const u16* __restrict__ Bt,
             u16* __restrict__ C, int M, int N, int K) {
  constexpr int SLOT = 20480;                 // u16 per slot: A[256][40] | B[256][40]
  __shared__ __align__(16) u16 LB[3 * SLOT];  // 122,880 B -> 1 block/CU
  const int nwg = gridDim.x;
  int wg = blockIdx.x;
  const int cpx = nwg >> 3;                   // XCD swizzle, nwg % 8 == 0
  wg = (wg & 7) * cpx + (wg >> 3);
  const int ntn = N >> 8;
  const int bm0 = (wg / ntn) << 8;
  const int bn0 = (wg % ntn) << 8;
  const int tid = threadIdx.x;
  const int wave = tid >> 6;
  const int lane = tid & 63;
  const int fr = lane & 15;
  const int g  = lane >> 4;
  const int wr = wave >> 2;                   // 0..1 (M)
  const int wc = wave & 3;                    // 0..3 (N)
  const int KT = K >> 5;

  f4 acc[8][4] = {};

  // stage inst i (0..4) of K-tile t into slot t%3.
  // chunk id c = i*512 + tid over 2560 chunks: [0,1280) = A, [1280,2560) = B.
  // row = c/5, sl = c%5 (sl==4 is the 16B pad slot; source re-reads col 0).
  auto STAGE = [&](int t, int i) {
    const int s = t - (t / 3) * 3;
    const int cb = i * 512 + wave * 64;       // wave-uniform
    const int cc0 = cb + lane;
    const bool isA = cb < 1280;               // wave-uniform (1280 % 64 == 0)
    const int cc = isA ? cc0 : cc0 - 1280;
    const int row = (cc * 52429) >> 18;       // cc/5 (exact for cc < 2560)
    const int sl = cc - row * 5;
    const u16* gsrc = (isA ? A + (size_t)(bm0 + row) * K
                           : Bt + (size_t)(bn0 + row) * K)
                      + (t << 5) + ((sl & 3) << 3);
    u16* ldst = &LB[s * SLOT + (isA ? 0 : 10240) + ((cb - (isA ? 0 : 1280)) << 3)];
    gl16(gsrc, ldst);
  };

  // prologue: tiles 0,1 staged; gate tile 0 (5 of tile 1 stay in flight)
  #pragma unroll
  for (int i = 0; i < 5; i++) STAGE(0, i);
  #pragma unroll
  for (int i = 0; i < 5; i++) STAGE(1, i);
  __builtin_amdgcn_sched_barrier(0);
  asm volatile("s_waitcnt vmcnt(5)" ::: "memory");
  __builtin_amdgcn_s_barrier();

  const int arow = wr * 128 + fr;
  const int brow = wc * 64 + fr;
  for (int kt = 0; kt < KT; kt++) {
    const int s = kt - (kt / 3) * 3;
    const u16* As = &LB[s * SLOT];
    const u16* Bs = &LB[s * SLOT + 10240];
    const bool pf = (kt + 2) < KT;
    // ---- phase 1: mi 0..3 ----
    sh8 af[4], bf[4];
    #pragma unroll
    for (int mi = 0; mi < 4; mi++)
      af[mi] = *(const sh8*)&As[(arow + mi * 16) * 40 + g * 8];
    #pragma unroll
    for (int ni = 0; ni < 4; ni++)
      bf[ni] = *(const sh8*)&Bs[(brow + ni * 16) * 40 + g * 8];
    if (pf) { STAGE(kt + 2, 0); STAGE(kt + 2, 1); STAGE(kt + 2, 2); }
    __builtin_amdgcn_s_barrier();
    __builtin_amdgcn_s_setprio(1);
    #pragma unroll
    for (int mi = 0; mi < 4; mi++)
      #pragma unroll
      for (int ni = 0; ni < 4; ni++)
        acc[mi][ni] = __builtin_amdgcn_mfma_f32_16x16x32_bf16(af[mi], bf[ni], acc[mi][ni], 0, 0, 0);
    __builtin_amdgcn_s_setprio(0);
    __builtin_amdgcn_s_barrier();
    // ---- phase 2: mi 4..7 ----
    sh8 af2[4];
    #pragma unroll
    for (int mi = 0; mi < 4; mi++)
      af2[mi] = *(const sh8*)&As[(arow + 64 + mi * 16) * 40 + g * 8];
    if (pf) { STAGE(kt + 2, 3); STAGE(kt + 2, 4); }
    __builtin_amdgcn_s_barrier();
    __builtin_amdgcn_s_setprio(1);
    #pragma unroll
    for (int mi = 0; mi < 4; mi++)
      #pragma unroll
      for (int ni = 0; ni < 4; ni++)
        acc[mi + 4][ni] = __builtin_amdgcn_mfma_f32_16x16x32_bf16(af2[mi], bf[ni], acc[mi + 4][ni], 0, 0, 0);
    __builtin_amdgcn_s_setprio(0);
    // gate: tile kt+1 must be resident after the barrier (in-order retirement:
    // <=5 outstanding => only tile kt+2's stages can remain in flight)
    if (kt < KT - 1) {
      __builtin_amdgcn_sched_barrier(0);
      if (pf) asm volatile("s_waitcnt vmcnt(5)" ::: "memory");
      else    asm volatile("s_waitcnt vmcnt(0)" ::: "memory");
    }
    __builtin_amdgcn_s_barrier();
  }

  const int rb = bm0 + wr * 128 + g * 4;
  const int cb2 = bn0 + wc * 64 + fr;
  #pragma unroll
  for (int mi = 0; mi < 8; mi++)
    #pragma unroll
    for (int ni = 0; ni < 4; ni++)
      #pragma unroll
      for (int r = 0; r < 4; r++)
        C[(size_t)(rb + mi * 16 + r) * N + cb2 + ni * 16] = f2bf(acc[mi][ni][r]);
}

// ---- bf16 MFMA GEMM (round-2 known-good), A[M][K] * Bt[N][K]^T -> C[M][N] ----
template<bool OUT_BF16>
__global__ __launch_bounds__(256, 2)
void k_gemm_bt(const u16* __restrict__ A, const u16* __restrict__ Bt,
               void* __restrict__ Cout, int M, int N, int K) {
  constexpr int LDT = 72;
  __shared__ __align__(16) u16 As[128 * LDT];
  __shared__ __align__(16) u16 Bs[128 * LDT];
  const int bm0 = blockIdx.y * 128;
  const int bn0 = blockIdx.x * 128;
  const int t = threadIdx.x;
  const int lane = t & 63;
  const int wave = t >> 6;
  const int wr = wave >> 1, wc = wave & 1;
  f4 acc[4][4] = {};
  const int sr = t >> 1;
  const int sc = (t & 1) * 32;
  const u16* Ap = A + (size_t)(bm0 + sr) * K + sc;
  const u16* Bp = Bt + (size_t)(bn0 + sr) * K + sc;
  u16* AsW = &As[sr * LDT + sc];
  u16* BsW = &Bs[sr * LDT + sc];
  const int fr = lane & 15;
  const int ko = (lane >> 4) * 8;
  for (int kt = 0; kt < K; kt += 64) {
    sh8 a0 = *(const sh8*)(Ap + kt);
    sh8 a1 = *(const sh8*)(Ap + kt + 8);
    sh8 a2 = *(const sh8*)(Ap + kt + 16);
    sh8 a3 = *(const sh8*)(Ap + kt + 24);
    sh8 b0 = *(const sh8*)(Bp + kt);
    sh8 b1 = *(const sh8*)(Bp + kt + 8);
    sh8 b2 = *(const sh8*)(Bp + kt + 16);
    sh8 b3 = *(const sh8*)(Bp + kt + 24);
    __syncthreads();
    *(sh8*)(AsW) = a0; *(sh8*)(AsW + 8) = a1; *(sh8*)(AsW + 16) = a2; *(sh8*)(AsW + 24) = a3;
    *(sh8*)(BsW) = b0; *(sh8*)(BsW + 8) = b1; *(sh8*)(BsW + 16) = b2; *(sh8*)(BsW + 24) = b3;
    __syncthreads();
    #pragma unroll
    for (int kh = 0; kh < 2; kh++) {
      sh8 af[4], bfv[4];
      const int kofs = kh * 32 + ko;
      #pragma unroll
      for (int mi = 0; mi < 4; mi++)
        af[mi] = *(const sh8*)&As[(wr * 64 + mi * 16 + fr) * LDT + kofs];
      #pragma unroll
      for (int ni = 0; ni < 4; ni++)
        bfv[ni] = *(const sh8*)&Bs[(wc * 64 + ni * 16 + fr) * LDT + kofs];
      #pragma unroll
      for (int mi = 0; mi < 4; mi++)
        #pragma unroll
        for (int ni = 0; ni < 4; ni++)
          acc[mi][ni] = __builtin_amdgcn_mfma_f32_16x16x32_bf16(af[mi], bfv[ni], acc[mi][ni], 0, 0, 0);
    }
  }
  const int rbase = bm0 + wr * 64 + (lane >> 4) * 4;
  const int cbase = bn0 + wc * 64 + fr;
  #pragma unroll
  for (int mi = 0; mi < 4; mi++)
    #pragma unroll
    for (int ni = 0; ni < 4; ni++)
      #pragma unroll
      for (int r = 0; r < 4; r++) {
        const size_t off = (size_t)(rbase + mi * 16 + r) * N + (cbase + ni * 16);
        if constexpr (OUT_BF16) ((u16*)Cout)[off] = f2bf(acc[mi][ni][r]);
        else                    ((float*)Cout)[off] = acc[mi][ni][r];
      }
}

// ---- mean-pool kc/vc -> kpb[bh][128][64] bf16, vpT[bh][64][128] bf16 (pad zeroed) ----
__global__ __launch_bounds__(64)
void k_pool(const u16* __restrict__ proj, u16* __restrict__ kpb, u16* __restrict__ vpT) {
  const int j = blockIdx.x;    // 0..127 (127 = zero pad)
  const int bh = blockIdx.y;   // 0..31
  const int b = bh >> 4, h = bh & 15;
  const int d = threadIdx.x;
  u16 kout = 0, vout = 0;
  if (j < 127) {
    const size_t base = (size_t)(b * 2048 + j * 16) * 5120;
    const size_t kcol = 3072 + h * 64 + d;
    const size_t vcol = 4096 + h * 64 + d;
    float ks = 0.f, vs = 0.f;
    #pragma unroll 4
    for (int r = 0; r < 32; r++) {
      const size_t off = base + (size_t)r * 5120;
      ks += bf2f(proj[off + kcol]);
      vs += bf2f(proj[off + vcol]);
    }
    kout = f2bf(ks * (1.f / 32.f));
    vout = f2bf(vs * (1.f / 32.f));
  }
  kpb[((size_t)bh * 128 + j) * 64 + d] = kout;
  vpT[((size_t)bh * 64 + d) * 128 + j] = vout;
}

// ---- transpose vl: proj cols [2048,3072) -> vlT[bh][64 d][2048 t] bf16 ----
__global__ __launch_bounds__(256)
void k_vt(const u16* __restrict__ proj, u16* __restrict__ vlT) {
  __shared__ u16 tile[64][72];
  const int tt = blockIdx.x;   // 0..31 token tile
  const int bh = blockIdx.y;   // 0..31
  const int b = bh >> 4, h = bh & 15;
  const int t = threadIdx.x;
  const int r = t >> 2;          // 0..63
  const int c0 = (t & 3) * 16;
  const u16* sp = proj + (size_t)(b * 2048 + tt * 64 + r) * 5120 + 2048 + h * 64 + c0;
  us8 v0 = *(const us8*)sp;
  us8 v1 = *(const us8*)(sp + 8);
  #pragma unroll
  for (int jj = 0; jj < 8; jj++) { tile[r][c0 + jj] = v0[jj]; tile[r][c0 + 8 + jj] = v1[jj]; }
  __syncthreads();
  u16* op = vlT + ((size_t)bh * 64 + r) * 2048 + tt * 64 + c0;
  #pragma unroll
  for (int jj = 0; jj < 16; jj++) op[jj] = tile[c0 + jj][r];
}

// ---------------- MFMA attention v5 (round-5 known-good) ----------------
__global__ __launch_bounds__(256)
void k_attn_mfma(const u16* __restrict__ proj, const u16* __restrict__ kpb,
                 const u16* __restrict__ vpT, const u16* __restrict__ vlT,
                 u16* __restrict__ yb) {
  __shared__ __align__(16) u16 SB[35328];
  const int qt = blockIdx.x;          // 0..31
  const int bh = blockIdx.y;          // 0..31
  const int b = bh >> 4, h = bh & 15;
  const int tid = threadIdx.x;
  const int wave = tid >> 6;
  const int lane = tid & 63;
  const int fr = lane & 15;
  const int g  = lane >> 4;
  const int ko = g * 8;
  const int q0 = qt * 64;
  const int wq0 = q0 + wave * 16;
  const int i_abs = wq0 + fr;

  const u16* prow = proj + (size_t)(b * 2048) * 5120;
  const u16* klb = prow + 1024 + h * 64;
  const u16* vltb = vlT + (size_t)bh * 64 * 2048;
  const u16* vptb = vpT + (size_t)bh * 8192;

  #pragma unroll
  for (int it = 0; it < 7; it++) {
    const int inst = it * 4 + wave;
    if (inst < 27) {
      const int c = inst * 64 + lane;
      const int row = c / 9;
      const int sl = c - row * 9;
      int jg = q0 - 128 + row; if (jg < 0) jg = 0;
      gl16(klb + (size_t)jg * 5120 + (sl & 7) * 8, &SB[inst * 512]);
    }
  }
  #pragma unroll
  for (int it = 0; it < 7; it++) {
    const int inst = it * 4 + wave;
    if (inst < 25) {
      const int c = inst * 64 + lane;
      const int row = c / 25;
      const int sl = c - row * 25;
      int tc = q0 - 128 + (sl < 24 ? sl : 0) * 8; if (tc < 0) tc = 0;
      gl16(vltb + (size_t)row * 2048 + tc, &SB[13824 + inst * 512]);
    }
  }
  #pragma unroll
  for (int it = 0; it < 5; it++) {
    const int inst = it * 4 + wave;
    if (inst < 17) {
      const int c = inst * 64 + lane;
      const int row = c / 17;
      const int sl = c - row * 17;
      gl16(vptb + (size_t)row * 128 + (sl & 15) * 8, &SB[26624 + inst * 512]);
    }
  }
  const sh8 bq0 = *(const sh8*)(prow + (size_t)i_abs * 5120 + h * 64 + ko);
  const sh8 bq1 = *(const sh8*)(prow + (size_t)i_abs * 5120 + h * 64 + 32 + ko);
  __syncthreads();

  f4 st[9];
  #pragma unroll
  for (int f = 0; f < 9; f++) st[f] = f4{0.f, 0.f, 0.f, 0.f};
  #pragma unroll
  for (int kh = 0; kh < 2; kh++) {
    const sh8 bq = kh ? bq1 : bq0;
    #pragma unroll
    for (int f = 0; f < 9; f++) {
      sh8 ak = *(const sh8*)&SB[(wave * 16 + f * 16 + fr) * 72 + kh * 32 + ko];
      st[f] = __builtin_amdgcn_mfma_f32_16x16x32_bf16(ak, bq, st[f], 0, 0, 0);
    }
  }
  const int nf = ((wq0 + 15) >> 8) + 1;
  f4 sc[8];
  #pragma unroll
  for (int f = 0; f < 8; f++) sc[f] = f4{0.f, 0.f, 0.f, 0.f};
  const u16* kpr = kpb + (size_t)bh * 8192;
  #pragma unroll
  for (int kh = 0; kh < 2; kh++) {
    const sh8 bq = kh ? bq1 : bq0;
    #pragma unroll
    for (int f = 0; f < 8; f++)
      if (f < nf) {
        sh8 ak = *(const sh8*)(kpr + (size_t)(f * 16 + fr) * 64 + kh * 32 + ko);
        sc[f] = __builtin_amdgcn_mfma_f32_16x16x32_bf16(ak, bq, sc[f], 0, 0, 0);
      }
  }

  const int klo = 128 - wq0;
  float m = -1e30f;
  #pragma unroll
  for (int f = 0; f < 9; f++)
    #pragma unroll
    for (int r = 0; r < 4; r++) {
      const int kk = f * 16 + g * 4 + r;
      const bool ok = (kk > fr) && (kk <= fr + 128) && (kk >= klo);
      const float v = ok ? st[f][r] * 0.125f : -1e30f;
      st[f][r] = v; m = fmaxf(m, v);
    }
  m = fmaxf(m, __shfl_xor(m, 16));
  m = fmaxf(m, __shfl_xor(m, 32));
  float l = 0.f;
  #pragma unroll
  for (int f = 0; f < 9; f++)
    #pragma unroll
    for (int r = 0; r < 4; r++) {
      const float p = __expf(st[f][r] - m);
      st[f][r] = p; l += p;
    }
  l += __shfl_xor(l, 16);
  l += __shfl_xor(l, 32);
  const float inv = 1.f / l;

  float m2 = -1e30f;
  #pragma unroll
  for (int f = 0; f < 8; f++)
    #pragma unroll
    for (int r = 0; r < 4; r++) {
      const int jj = f * 16 + g * 4 + r;
      const bool ok = (jj <= 126) && (16 * jj <= i_abs);
      const float v = ok ? sc[f][r] * 0.125f : -1e30f;
      sc[f][r] = v; m2 = fmaxf(m2, v);
    }
  m2 = fmaxf(m2, __shfl_xor(m2, 16));
  m2 = fmaxf(m2, __shfl_xor(m2, 32));
  float l2 = 0.f;
  #pragma unroll
  for (int f = 0; f < 8; f++)
    #pragma unroll
    for (int r = 0; r < 4; r++) {
      const float p = __expf(sc[f][r] - m2);
      sc[f][r] = p; l2 += p;
    }
  l2 += __shfl_xor(l2, 16);
  l2 += __shfl_xor(l2, 32);
  const float inv2 = 1.f / l2;

  __syncthreads();

  u16* Pw = &SB[wave * 2688];
  #pragma unroll
  for (int f = 0; f < 9; f++) {
    ui2 pk;
    pk[0] = (u32)f2bf(st[f][0] * inv) | ((u32)f2bf(st[f][1] * inv) << 16);
    pk[1] = (u32)f2bf(st[f][2] * inv) | ((u32)f2bf(st[f][3] * inv) << 16);
    *(ui2*)&Pw[fr * 168 + f * 16 + g * 4] = pk;
  }
  *(ui2*)&Pw[fr * 168 + 144 + g * 4] = ui2{0u, 0u};

  f4 yacc[4];
  #pragma unroll
  for (int ni = 0; ni < 4; ni++) yacc[ni] = f4{0.f, 0.f, 0.f, 0.f};
  #pragma unroll
  for (int ks = 0; ks < 5; ks++) {
    sh8 pa = *(const sh8*)&Pw[fr * 168 + ks * 32 + ko];
    const int col = wave * 16 + ks * 32 + ko;
    #pragma unroll
    for (int ni = 0; ni < 4; ni++) {
      sh8 vb = *(const sh8*)&SB[13824 + (ni * 16 + fr) * 200 + col];
      yacc[ni] = __builtin_amdgcn_mfma_f32_16x16x32_bf16(pa, vb, yacc[ni], 0, 0, 0);
    }
  }

  const int nks = (nf + 1) >> 1;
  #pragma unroll
  for (int f = 0; f < 8; f++)
    if (f < nf) {
      ui2 pk;
      pk[0] = (u32)f2bf(sc[f][0] * inv2) | ((u32)f2bf(sc[f][1] * inv2) << 16);
      pk[1] = (u32)f2bf(sc[f][2] * inv2) | ((u32)f2bf(sc[f][3] * inv2) << 16);
      *(ui2*)&Pw[fr * 168 + f * 16 + g * 4] = pk;
    }
  if (nf & 1)
    *(ui2*)&Pw[fr * 168 + nf * 16 + g * 4] = ui2{0u, 0u};

  #pragma unroll
  for (int ks = 0; ks < 4; ks++)
    if (ks < nks) {
      sh8 pa = *(const sh8*)&Pw[fr * 168 + ks * 32 + ko];
      #pragma unroll
      for (int ni = 0; ni < 4; ni++) {
        sh8 vb = *(const sh8*)&SB[26624 + (ni * 16 + fr) * 136 + ks * 32 + ko];
        yacc[ni] = __builtin_amdgcn_mfma_f32_16x16x32_bf16(pa, vb, yacc[ni], 0, 0, 0);
      }
    }

  #pragma unroll
  for (int ni = 0; ni < 4; ni++)
    #pragma unroll
    for (int r = 0; r < 4; r++)
      Pw[(4 * g + r) * 72 + ni * 16 + fr] = f2bf(yacc[ni][r]);
  {
    const int row = lane >> 2;
    const int c0 = (lane & 3) * 16;
    u16* gy = yb + (size_t)(b * 2048 + wq0 + row) * 1024 + h * 64 + c0;
    *(us8*)gy       = *(const us8*)&Pw[row * 72 + c0];
    *(us8*)(gy + 8) = *(const us8*)&Pw[row * 72 + c0 + 8];
  }
}

extern "C" void kernel_launch(void* const* d_in, const int* in_sizes, int n_in,
                              void* d_out, int out_size, void* d_ws, size_t ws_size,
                              hipStream_t stream) {
  const float* x  = (const float*)d_in[0];
  const float* Wq = (const float*)d_in[1];
  const float* Wl = (const float*)d_in[2];
  const float* Wc = (const float*)d_in[3];
  const float* Wo = (const float*)d_in[4];
  // dkc/dvc unused: n_def == 0 at T=2048.
  float* out = (float*)d_out;
  char* ws = (char*)d_ws;
  // workspace (72.4 MB): vlT aliases xb (xb dead after gemm1)
  u16* xb   = (u16*)(ws);                       //  8 MB  x bf16 [4096][1024]
  u16* vlT  = (u16*)(ws);                       //  8 MB  vl^T bf16 [32][64][2048] (after gemm1)
  u16* Wt   = (u16*)(ws + 8388608);             // 12 MB  weights^T bf16 [6144][1024]
  u16* proj = (u16*)(ws + 20971520);            // 40 MB  [4096][5120] q|kl|vl|kc|vc
  u16* kpb  = (u16*)(ws + 62914560);            // 512 KB pooled K bf16 [32][128][64]
  u16* vpT  = (u16*)(ws + 63438848);            // 512 KB pooled V^T bf16 [32][64][128]
  u16* yb   = (u16*)(ws + 63963136);            //  8 MB  y bf16 [4096][1024]

  k_cvt_bf16<<<2048, 256, 0, stream>>>(x, xb, 4194304 / 8);
  k_prep_w<<<dim3(96, 16), 256, 0, stream>>>(Wq, Wl, Wc, Wo, Wt);
  k_gemm8<<<320, 512, 0, stream>>>(xb, Wt, proj, 4096, 5120, 1024);
  k_pool<<<dim3(128, 32), 64, 0, stream>>>(proj, kpb, vpT);
  k_vt<<<dim3(32, 32), 256, 0, stream>>>(proj, vlT);
  k_attn_mfma<<<dim3(32, 32), 256, 0, stream>>>(proj, kpb, vpT, vlT, yb);
  k_gemm_bt<false><<<dim3(8, 32), 256, 0, stream>>>(yb, Wt + (size_t)5120 * 1024, out, 4096, 1024, 1024);
}

// Round 7
// 149.255 us; speedup vs baseline: 1.1430x; 1.1430x over previous
//
#include <hip/hip_runtime.h>

typedef unsigned short u16;
typedef unsigned int u32;
typedef __attribute__((ext_vector_type(8))) short sh8;           // 8 bf16 (4 VGPR)
typedef __attribute__((ext_vector_type(8))) unsigned short us8;
typedef __attribute__((ext_vector_type(2))) unsigned int ui2;
typedef __attribute__((ext_vector_type(4))) float f4;

__device__ __forceinline__ float bf2f(u16 u) {
  union { unsigned u; float f; } v; v.u = ((unsigned)u) << 16; return v.f;
}
__device__ __forceinline__ u16 f2bf(float f) {
  union { float f; unsigned u; } v; v.f = f;
  unsigned r = v.u + 0x7fffu + ((v.u >> 16) & 1u);   // RNE, inputs finite
  return (u16)(r >> 16);
}
// pack 4 f32 -> 4 bf16 (RNE) in 2 insts
__device__ __forceinline__ ui2 pk4(float a, float b, float c, float d) {
  u32 lo, hi;
  asm("v_cvt_pk_bf16_f32 %0, %1, %2" : "=v"(lo) : "v"(a), "v"(b));
  asm("v_cvt_pk_bf16_f32 %0, %1, %2" : "=v"(hi) : "v"(c), "v"(d));
  ui2 r; r[0] = lo; r[1] = hi; return r;
}
// async global->LDS, 16B per lane; dest = wave-uniform base + lane*16
__device__ __forceinline__ void gl16(const void* g, void* l) {
  __builtin_amdgcn_global_load_lds(
      (const __attribute__((address_space(1))) unsigned int*)g,
      (__attribute__((address_space(3))) unsigned int*)l, 16, 0, 0);
}

// ---------------- f32 -> bf16, 8 elems/thread ----------------
__global__ __launch_bounds__(256)
void k_cvt_bf16(const float* __restrict__ in, u16* __restrict__ out, int n8) {
  int idx = blockIdx.x * 256 + threadIdx.x;
  if (idx >= n8) return;
  const f4* p = (const f4*)in + (size_t)idx * 2;
  f4 a = p[0], b = p[1];
  us8 o;
  o[0] = f2bf(a[0]); o[1] = f2bf(a[1]); o[2] = f2bf(a[2]); o[3] = f2bf(a[3]);
  o[4] = f2bf(b[0]); o[5] = f2bf(b[1]); o[6] = f2bf(b[2]); o[7] = f2bf(b[3]);
  ((us8*)out)[idx] = o;
}

// ------- weights: concat + transpose to Wt[n][k] bf16, n in [0,6144) -------
__global__ __launch_bounds__(256)
void k_prep_w(const float* __restrict__ Wq, const float* __restrict__ Wl,
              const float* __restrict__ Wc, const float* __restrict__ Wo,
              u16* __restrict__ Wt) {
  __shared__ u16 tile[64][65];
  const int n0 = blockIdx.x * 64;
  const int k0 = blockIdx.y * 64;
  const float* src; int ld, col0;
  if (n0 < 1024)      { src = Wq; ld = 1024; col0 = n0; }
  else if (n0 < 3072) { src = Wl; ld = 2048; col0 = n0 - 1024; }
  else if (n0 < 5120) { src = Wc; ld = 2048; col0 = n0 - 3072; }
  else                { src = Wo; ld = 1024; col0 = n0 - 5120; }
  const int t = threadIdx.x;
  const int r = t >> 2;          // 0..63
  const int c0 = (t & 3) * 16;   // 0,16,32,48
  const float* sp = src + (size_t)(k0 + r) * ld + col0 + c0;
  #pragma unroll
  for (int j = 0; j < 16; j++) tile[r][c0 + j] = f2bf(sp[j]);
  __syncthreads();
  u16* op = Wt + (size_t)(n0 + r) * 1024 + k0 + c0;
  #pragma unroll
  for (int j = 0; j < 16; j++) op[j] = tile[c0 + j][r];
}

// ---- bf16 MFMA GEMM (round-2 known-good), A[M][K] * Bt[N][K]^T -> C[M][N] ----
template<bool OUT_BF16>
__global__ __launch_bounds__(256, 4)
void k_gemm_bt(const u16* __restrict__ A, const u16* __restrict__ Bt,
               void* __restrict__ Cout, int M, int N, int K) {
  constexpr int LDT = 72;
  __shared__ __align__(16) u16 As[128 * LDT];
  __shared__ __align__(16) u16 Bs[128 * LDT];
  const int bm0 = blockIdx.y * 128;
  const int bn0 = blockIdx.x * 128;
  const int t = threadIdx.x;
  const int lane = t & 63;
  const int wave = t >> 6;
  const int wr = wave >> 1, wc = wave & 1;
  f4 acc[4][4] = {};
  const int sr = t >> 1;
  const int sc = (t & 1) * 32;
  const u16* Ap = A + (size_t)(bm0 + sr) * K + sc;
  const u16* Bp = Bt + (size_t)(bn0 + sr) * K + sc;
  u16* AsW = &As[sr * LDT + sc];
  u16* BsW = &Bs[sr * LDT + sc];
  const int fr = lane & 15;
  const int ko = (lane >> 4) * 8;
  for (int kt = 0; kt < K; kt += 64) {
    sh8 a0 = *(const sh8*)(Ap + kt);
    sh8 a1 = *(const sh8*)(Ap + kt + 8);
    sh8 a2 = *(const sh8*)(Ap + kt + 16);
    sh8 a3 = *(const sh8*)(Ap + kt + 24);
    sh8 b0 = *(const sh8*)(Bp + kt);
    sh8 b1 = *(const sh8*)(Bp + kt + 8);
    sh8 b2 = *(const sh8*)(Bp + kt + 16);
    sh8 b3 = *(const sh8*)(Bp + kt + 24);
    __syncthreads();
    *(sh8*)(AsW) = a0; *(sh8*)(AsW + 8) = a1; *(sh8*)(AsW + 16) = a2; *(sh8*)(AsW + 24) = a3;
    *(sh8*)(BsW) = b0; *(sh8*)(BsW + 8) = b1; *(sh8*)(BsW + 16) = b2; *(sh8*)(BsW + 24) = b3;
    __syncthreads();
    #pragma unroll
    for (int kh = 0; kh < 2; kh++) {
      sh8 af[4], bfv[4];
      const int kofs = kh * 32 + ko;
      #pragma unroll
      for (int mi = 0; mi < 4; mi++)
        af[mi] = *(const sh8*)&As[(wr * 64 + mi * 16 + fr) * LDT + kofs];
      #pragma unroll
      for (int ni = 0; ni < 4; ni++)
        bfv[ni] = *(const sh8*)&Bs[(wc * 64 + ni * 16 + fr) * LDT + kofs];
      #pragma unroll
      for (int mi = 0; mi < 4; mi++)
        #pragma unroll
        for (int ni = 0; ni < 4; ni++)
          acc[mi][ni] = __builtin_amdgcn_mfma_f32_16x16x32_bf16(af[mi], bfv[ni], acc[mi][ni], 0, 0, 0);
    }
  }
  const int rbase = bm0 + wr * 64 + (lane >> 4) * 4;
  const int cbase = bn0 + wc * 64 + fr;
  #pragma unroll
  for (int mi = 0; mi < 4; mi++)
    #pragma unroll
    for (int ni = 0; ni < 4; ni++)
      #pragma unroll
      for (int r = 0; r < 4; r++) {
        const size_t off = (size_t)(rbase + mi * 16 + r) * N + (cbase + ni * 16);
        if constexpr (OUT_BF16) ((u16*)Cout)[off] = f2bf(acc[mi][ni][r]);
        else                    ((float*)Cout)[off] = acc[mi][ni][r];
      }
}

// ---- mean-pool kc/vc -> kpb[bh][128][64] bf16, vpT[bh][64][128] bf16 (pad zeroed) ----
__global__ __launch_bounds__(64)
void k_pool(const u16* __restrict__ proj, u16* __restrict__ kpb, u16* __restrict__ vpT) {
  const int j = blockIdx.x;    // 0..127 (127 = zero pad)
  const int bh = blockIdx.y;   // 0..31
  const int b = bh >> 4, h = bh & 15;
  const int d = threadIdx.x;
  u16 kout = 0, vout = 0;
  if (j < 127) {
    const size_t base = (size_t)(b * 2048 + j * 16) * 5120;
    const size_t kcol = 3072 + h * 64 + d;
    const size_t vcol = 4096 + h * 64 + d;
    float ks = 0.f, vs = 0.f;
    #pragma unroll 4
    for (int r = 0; r < 32; r++) {
      const size_t off = base + (size_t)r * 5120;
      ks += bf2f(proj[off + kcol]);
      vs += bf2f(proj[off + vcol]);
    }
    kout = f2bf(ks * (1.f / 32.f));
    vout = f2bf(vs * (1.f / 32.f));
  }
  kpb[((size_t)bh * 128 + j) * 64 + d] = kout;
  vpT[((size_t)bh * 64 + d) * 128 + j] = vout;
}

// ---- transpose vl: proj cols [2048,3072) -> vlT[bh][64 d][2048 t] bf16 ----
__global__ __launch_bounds__(256)
void k_vt(const u16* __restrict__ proj, u16* __restrict__ vlT) {
  __shared__ u16 tile[64][72];
  const int tt = blockIdx.x;   // 0..31 token tile
  const int bh = blockIdx.y;   // 0..31
  const int b = bh >> 4, h = bh & 15;
  const int t = threadIdx.x;
  const int r = t >> 2;          // 0..63
  const int c0 = (t & 3) * 16;
  const u16* sp = proj + (size_t)(b * 2048 + tt * 64 + r) * 5120 + 2048 + h * 64 + c0;
  us8 v0 = *(const us8*)sp;
  us8 v1 = *(const us8*)(sp + 8);
  #pragma unroll
  for (int jj = 0; jj < 8; jj++) { tile[r][c0 + jj] = v0[jj]; tile[r][c0 + 8 + jj] = v1[jj]; }
  __syncthreads();
  u16* op = vlT + ((size_t)bh * 64 + r) * 2048 + tt * 64 + c0;
  #pragma unroll
  for (int jj = 0; jj < 16; jj++) op[jj] = tile[c0 + jj][r];
}

// -------- attention LOCAL phase: writes y_local (pre-normalized) to yb --------
// Block = (qt, bh); wave owns 16 queries; 144-key window per wave.
// LDS: KL[192][72] @0 (27648B) -> P after barrier2; VL[64][200] @13824 (25600B).
__global__ __launch_bounds__(256)
void k_attn_local(const u16* __restrict__ proj, const u16* __restrict__ vlT,
                  u16* __restrict__ yb) {
  __shared__ __align__(16) u16 SB[26688];   // 53376 B -> 3 blocks/CU
  const int qt = blockIdx.x;          // 0..31
  const int bh = blockIdx.y;          // 0..31
  const int b = bh >> 4, h = bh & 15;
  const int tid = threadIdx.x;
  const int wave = tid >> 6;
  const int lane = tid & 63;
  const int fr = lane & 15;
  const int g  = lane >> 4;
  const int ko = g * 8;
  const int q0 = qt * 64;
  const int wq0 = q0 + wave * 16;
  const int i_abs = wq0 + fr;

  const u16* prow = proj + (size_t)(b * 2048) * 5120;
  const u16* klb = prow + 1024 + h * 64;
  const u16* vltb = vlT + (size_t)bh * 64 * 2048;

  // KL: 192 rows x 9 chunks (8 data + 1 pad) = 27 insts
  #pragma unroll
  for (int it = 0; it < 7; it++) {
    const int inst = it * 4 + wave;
    if (inst < 27) {
      const int c = inst * 64 + lane;
      const int row = c / 9;
      const int sl = c - row * 9;
      int jg = q0 - 128 + row; if (jg < 0) jg = 0;
      gl16(klb + (size_t)jg * 5120 + (sl & 7) * 8, &SB[inst * 512]);
    }
  }
  // VL: 64 rows x 25 chunks (24 data + 1 pad) = 25 insts
  #pragma unroll
  for (int it = 0; it < 7; it++) {
    const int inst = it * 4 + wave;
    if (inst < 25) {
      const int c = inst * 64 + lane;
      const int row = c / 25;
      const int sl = c - row * 25;
      int tc = q0 - 128 + (sl < 24 ? sl : 0) * 8; if (tc < 0) tc = 0;
      gl16(vltb + (size_t)row * 2048 + tc, &SB[13824 + inst * 512]);
    }
  }
  const sh8 bq0 = *(const sh8*)(prow + (size_t)i_abs * 5120 + h * 64 + ko);
  const sh8 bq1 = *(const sh8*)(prow + (size_t)i_abs * 5120 + h * 64 + 32 + ko);
  __syncthreads();   // barrier 1: stages resident

  // QK: 9 frags (window j = wq0-128+kk, kk in [0,144))
  f4 st[9];
  #pragma unroll
  for (int f = 0; f < 9; f++) st[f] = f4{0.f, 0.f, 0.f, 0.f};
  #pragma unroll
  for (int kh = 0; kh < 2; kh++) {
    const sh8 bq = kh ? bq1 : bq0;
    #pragma unroll
    for (int f = 0; f < 9; f++) {
      sh8 ak = *(const sh8*)&SB[(wave * 16 + f * 16 + fr) * 72 + kh * 32 + ko];
      st[f] = __builtin_amdgcn_mfma_f32_16x16x32_bf16(ak, bq, st[f], 0, 0, 0);
    }
  }
  const int klo = 128 - wq0;
  float m = -1e30f;
  #pragma unroll
  for (int f = 0; f < 9; f++)
    #pragma unroll
    for (int r = 0; r < 4; r++) {
      const int kk = f * 16 + g * 4 + r;
      const bool ok = (kk > fr) && (kk <= fr + 128) && (kk >= klo);
      const float v = ok ? st[f][r] * 0.125f : -1e30f;
      st[f][r] = v; m = fmaxf(m, v);
    }
  m = fmaxf(m, __shfl_xor(m, 16));
  m = fmaxf(m, __shfl_xor(m, 32));
  float l = 0.f;
  #pragma unroll
  for (int f = 0; f < 9; f++)
    #pragma unroll
    for (int r = 0; r < 4; r++) {
      const float p = __expf(st[f][r] - m);
      st[f][r] = p; l += p;
    }
  l += __shfl_xor(l, 16);
  l += __shfl_xor(l, 32);
  const float inv = 1.f / l;      // l>0: key j=i always allowed

  __syncthreads();   // barrier 2: KL reads done; region becomes P

  u16* Pw = &SB[wave * 2688];     // [16][168]
  #pragma unroll
  for (int f = 0; f < 9; f++)
    *(ui2*)&Pw[fr * 168 + f * 16 + g * 4] =
        pk4(st[f][0] * inv, st[f][1] * inv, st[f][2] * inv, st[f][3] * inv);
  *(ui2*)&Pw[fr * 168 + 144 + g * 4] = ui2{0u, 0u};   // zero pad kk [144,160)

  f4 yacc[4];
  #pragma unroll
  for (int ni = 0; ni < 4; ni++) yacc[ni] = f4{0.f, 0.f, 0.f, 0.f};
  #pragma unroll
  for (int ks = 0; ks < 5; ks++) {
    sh8 pa = *(const sh8*)&Pw[fr * 168 + ks * 32 + ko];
    const int col = wave * 16 + ks * 32 + ko;          // < 208, pad-safe
    #pragma unroll
    for (int ni = 0; ni < 4; ni++) {
      sh8 vb = *(const sh8*)&SB[13824 + (ni * 16 + fr) * 200 + col];
      yacc[ni] = __builtin_amdgcn_mfma_f32_16x16x32_bf16(pa, vb, yacc[ni], 0, 0, 0);
    }
  }

  // Y transpose via own P region, coalesced store
  #pragma unroll
  for (int ni = 0; ni < 4; ni++)
    #pragma unroll
    for (int r = 0; r < 4; r++)
      Pw[(4 * g + r) * 72 + ni * 16 + fr] = f2bf(yacc[ni][r]);
  {
    const int row = lane >> 2;
    const int c0 = (lane & 3) * 16;
    u16* gy = yb + (size_t)(b * 2048 + wq0 + row) * 1024 + h * 64 + c0;
    *(us8*)gy       = *(const us8*)&Pw[row * 72 + c0];
    *(us8*)(gy + 8) = *(const us8*)&Pw[row * 72 + c0 + 8];
  }
}

// -------- attention COMPRESSED phase: yb += y_comp (runs after local) --------
// Block = (qt, bh). LDS: KC[128][72] @0 (18432B) -> P after barrier2;
// VC[64][136] @9216 (17408B). KC/VC identical across qt -> L2-hot staging.
__global__ __launch_bounds__(256)
void k_attn_comp(const u16* __restrict__ proj, const u16* __restrict__ kpb,
                 const u16* __restrict__ vpT, u16* __restrict__ yb) {
  __shared__ __align__(16) u16 SB[17920];   // 35840 B -> 4 blocks/CU
  const int qt = blockIdx.x;
  const int bh = blockIdx.y;
  const int b = bh >> 4, h = bh & 15;
  const int tid = threadIdx.x;
  const int wave = tid >> 6;
  const int lane = tid & 63;
  const int fr = lane & 15;
  const int g  = lane >> 4;
  const int ko = g * 8;
  const int wq0 = qt * 64 + wave * 16;
  const int i_abs = wq0 + fr;

  const u16* prow = proj + (size_t)(b * 2048) * 5120;
  const u16* kpr = kpb + (size_t)bh * 8192;
  const u16* vptb = vpT + (size_t)bh * 8192;

  // KC: 128 rows x 9 chunks = 18 insts
  #pragma unroll
  for (int it = 0; it < 5; it++) {
    const int inst = it * 4 + wave;
    if (inst < 18) {
      const int c = inst * 64 + lane;
      const int row = c / 9;
      const int sl = c - row * 9;
      gl16(kpr + (size_t)row * 64 + (sl & 7) * 8, &SB[inst * 512]);
    }
  }
  // VC: 64 rows x 17 chunks = 17 insts
  #pragma unroll
  for (int it = 0; it < 5; it++) {
    const int inst = it * 4 + wave;
    if (inst < 17) {
      const int c = inst * 64 + lane;
      const int row = c / 17;
      const int sl = c - row * 17;
      gl16(vptb + (size_t)row * 128 + (sl & 15) * 8, &SB[9216 + inst * 512]);
    }
  }
  const sh8 bq0 = *(const sh8*)(prow + (size_t)i_abs * 5120 + h * 64 + ko);
  const sh8 bq1 = *(const sh8*)(prow + (size_t)i_abs * 5120 + h * 64 + 32 + ko);
  // y_local readback (store pattern), issued early to hide latency
  const int yrow = lane >> 2;
  const int yc0 = (lane & 3) * 16;
  u16* gy = yb + (size_t)(b * 2048 + wq0 + yrow) * 1024 + h * 64 + yc0;
  const us8 yold0 = *(const us8*)gy;
  const us8 yold1 = *(const us8*)(gy + 8);
  __syncthreads();   // barrier 1

  const int nf = ((wq0 + 15) >> 8) + 1;   // 1..8, wave-uniform
  f4 sc[8];
  #pragma unroll
  for (int f = 0; f < 8; f++) sc[f] = f4{0.f, 0.f, 0.f, 0.f};
  #pragma unroll
  for (int kh = 0; kh < 2; kh++) {
    const sh8 bq = kh ? bq1 : bq0;
    #pragma unroll
    for (int f = 0; f < 8; f++)
      if (f < nf) {
        sh8 ak = *(const sh8*)&SB[(f * 16 + fr) * 72 + kh * 32 + ko];
        sc[f] = __builtin_amdgcn_mfma_f32_16x16x32_bf16(ak, bq, sc[f], 0, 0, 0);
      }
  }
  float m2 = -1e30f;
  #pragma unroll
  for (int f = 0; f < 8; f++)
    #pragma unroll
    for (int r = 0; r < 4; r++) {
      const int jj = f * 16 + g * 4 + r;
      const bool ok = (jj <= 126) && (16 * jj <= i_abs);
      const float v = ok ? sc[f][r] * 0.125f : -1e30f;
      sc[f][r] = v; m2 = fmaxf(m2, v);
    }
  m2 = fmaxf(m2, __shfl_xor(m2, 16));
  m2 = fmaxf(m2, __shfl_xor(m2, 32));
  float l2 = 0.f;
  #pragma unroll
  for (int f = 0; f < 8; f++)
    #pragma unroll
    for (int r = 0; r < 4; r++) {
      const float p = __expf(sc[f][r] - m2);
      sc[f][r] = p; l2 += p;
    }
  l2 += __shfl_xor(l2, 16);
  l2 += __shfl_xor(l2, 32);
  const float inv2 = 1.f / l2;    // l2>0: block 0 allowed for every i

  __syncthreads();   // barrier 2: KC reads done; region becomes P

  u16* Pw = &SB[wave * 2176];     // [16][136]
  #pragma unroll
  for (int f = 0; f < 8; f++)
    if (f < nf)
      *(ui2*)&Pw[fr * 136 + f * 16 + g * 4] =
          pk4(sc[f][0] * inv2, sc[f][1] * inv2, sc[f][2] * inv2, sc[f][3] * inv2);
  if (nf & 1)
    *(ui2*)&Pw[fr * 136 + nf * 16 + g * 4] = ui2{0u, 0u};   // pad odd frag

  f4 yacc[4];
  #pragma unroll
  for (int ni = 0; ni < 4; ni++) yacc[ni] = f4{0.f, 0.f, 0.f, 0.f};
  const int nks = (nf + 1) >> 1;
  #pragma unroll
  for (int ks = 0; ks < 4; ks++)
    if (ks < nks) {
      sh8 pa = *(const sh8*)&Pw[fr * 136 + ks * 32 + ko];
      #pragma unroll
      for (int ni = 0; ni < 4; ni++) {
        sh8 vb = *(const sh8*)&SB[9216 + (ni * 16 + fr) * 136 + ks * 32 + ko];
        yacc[ni] = __builtin_amdgcn_mfma_f32_16x16x32_bf16(pa, vb, yacc[ni], 0, 0, 0);
      }
    }

  // Y transpose via own P region; add y_local; coalesced store
  #pragma unroll
  for (int ni = 0; ni < 4; ni++)
    #pragma unroll
    for (int r = 0; r < 4; r++)
      Pw[(4 * g + r) * 72 + ni * 16 + fr] = f2bf(yacc[ni][r]);
  {
    const us8 yc = *(const us8*)&Pw[yrow * 72 + yc0];
    const us8 yc2 = *(const us8*)&Pw[yrow * 72 + yc0 + 8];
    us8 o0, o1;
    #pragma unroll
    for (int jj = 0; jj < 8; jj++) {
      o0[jj] = f2bf(bf2f(yold0[jj]) + bf2f(yc[jj]));
      o1[jj] = f2bf(bf2f(yold1[jj]) + bf2f(yc2[jj]));
    }
    *(us8*)gy       = o0;
    *(us8*)(gy + 8) = o1;
  }
}

extern "C" void kernel_launch(void* const* d_in, const int* in_sizes, int n_in,
                              void* d_out, int out_size, void* d_ws, size_t ws_size,
                              hipStream_t stream) {
  const float* x  = (const float*)d_in[0];
  const float* Wq = (const float*)d_in[1];
  const float* Wl = (const float*)d_in[2];
  const float* Wc = (const float*)d_in[3];
  const float* Wo = (const float*)d_in[4];
  // dkc/dvc unused: n_def == 0 at T=2048.
  float* out = (float*)d_out;
  char* ws = (char*)d_ws;
  // workspace (72.4 MB): vlT aliases xb (xb dead after gemm1)
  u16* xb   = (u16*)(ws);                       //  8 MB  x bf16 [4096][1024]
  u16* vlT  = (u16*)(ws);                       //  8 MB  vl^T bf16 [32][64][2048] (after gemm1)
  u16* Wt   = (u16*)(ws + 8388608);             // 12 MB  weights^T bf16 [6144][1024]
  u16* proj = (u16*)(ws + 20971520);            // 40 MB  [4096][5120] q|kl|vl|kc|vc
  u16* kpb  = (u16*)(ws + 62914560);            // 512 KB pooled K bf16 [32][128][64]
  u16* vpT  = (u16*)(ws + 63438848);            // 512 KB pooled V^T bf16 [32][64][128]
  u16* yb   = (u16*)(ws + 63963136);            //  8 MB  y bf16 [4096][1024]

  k_cvt_bf16<<<2048, 256, 0, stream>>>(x, xb, 4194304 / 8);
  k_prep_w<<<dim3(96, 16), 256, 0, stream>>>(Wq, Wl, Wc, Wo, Wt);
  k_gemm_bt<true><<<dim3(40, 32), 256, 0, stream>>>(xb, Wt, proj, 4096, 5120, 1024);
  k_pool<<<dim3(128, 32), 64, 0, stream>>>(proj, kpb, vpT);
  k_vt<<<dim3(32, 32), 256, 0, stream>>>(proj, vlT);
  k_attn_local<<<dim3(32, 32), 256, 0, stream>>>(proj, vlT, yb);
  k_attn_comp<<<dim3(32, 32), 256, 0, stream>>>(proj, kpb, vpT, yb);
  k_gemm_bt<false><<<dim3(8, 32), 256, 0, stream>>>(yb, Wt + (size_t)5120 * 1024, out, 4096, 1024, 1024);
}

// Round 8
// 141.359 us; speedup vs baseline: 1.2068x; 1.0559x over previous
//
#include <hip/hip_runtime.h>

typedef unsigned short u16;
typedef unsigned int u32;
typedef __attribute__((ext_vector_type(8))) short sh8;           // 8 bf16 (4 VGPR)
typedef __attribute__((ext_vector_type(8))) unsigned short us8;
typedef __attribute__((ext_vector_type(2))) unsigned int ui2;
typedef __attribute__((ext_vector_type(4))) float f4;

__device__ __forceinline__ float bf2f(u16 u) {
  union { unsigned u; float f; } v; v.u = ((unsigned)u) << 16; return v.f;
}
__device__ __forceinline__ u16 f2bf(float f) {
  union { float f; unsigned u; } v; v.f = f;
  unsigned r = v.u + 0x7fffu + ((v.u >> 16) & 1u);   // RNE, inputs finite
  return (u16)(r >> 16);
}
// pack 4 f32 -> 4 bf16 (RNE) in 2 insts
__device__ __forceinline__ ui2 pk4(float a, float b, float c, float d) {
  u32 lo, hi;
  asm("v_cvt_pk_bf16_f32 %0, %1, %2" : "=v"(lo) : "v"(a), "v"(b));
  asm("v_cvt_pk_bf16_f32 %0, %1, %2" : "=v"(hi) : "v"(c), "v"(d));
  ui2 r; r[0] = lo; r[1] = hi; return r;
}
// async global->LDS, 16B per lane; dest = wave-uniform base + lane*16
__device__ __forceinline__ void gl16(const void* g, void* l) {
  __builtin_amdgcn_global_load_lds(
      (const __attribute__((address_space(1))) unsigned int*)g,
      (__attribute__((address_space(3))) unsigned int*)l, 16, 0, 0);
}

// ---------------- f32 -> bf16, 8 elems/thread ----------------
__global__ __launch_bounds__(256)
void k_cvt_bf16(const float* __restrict__ in, u16* __restrict__ out, int n8) {
  int idx = blockIdx.x * 256 + threadIdx.x;
  if (idx >= n8) return;
  const f4* p = (const f4*)in + (size_t)idx * 2;
  f4 a = p[0], b = p[1];
  us8 o;
  o[0] = f2bf(a[0]); o[1] = f2bf(a[1]); o[2] = f2bf(a[2]); o[3] = f2bf(a[3]);
  o[4] = f2bf(b[0]); o[5] = f2bf(b[1]); o[6] = f2bf(b[2]); o[7] = f2bf(b[3]);
  ((us8*)out)[idx] = o;
}

// ------- weights: concat + transpose to Wt[n][k] bf16, n in [0,6144) -------
__global__ __launch_bounds__(256)
void k_prep_w(const float* __restrict__ Wq, const float* __restrict__ Wl,
              const float* __restrict__ Wc, const float* __restrict__ Wo,
              u16* __restrict__ Wt) {
  __shared__ u16 tile[64][65];
  const int n0 = blockIdx.x * 64;
  const int k0 = blockIdx.y * 64;
  const float* src; int ld, col0;
  if (n0 < 1024)      { src = Wq; ld = 1024; col0 = n0; }
  else if (n0 < 3072) { src = Wl; ld = 2048; col0 = n0 - 1024; }
  else if (n0 < 5120) { src = Wc; ld = 2048; col0 = n0 - 3072; }
  else                { src = Wo; ld = 1024; col0 = n0 - 5120; }
  const int t = threadIdx.x;
  const int r = t >> 2;          // 0..63
  const int c0 = (t & 3) * 16;   // 0,16,32,48
  const f4* sp = (const f4*)(src + (size_t)(k0 + r) * ld + col0 + c0);
  const f4 va = sp[0], vb = sp[1], vc = sp[2], vd = sp[3];
  #pragma unroll
  for (int j = 0; j < 4; j++) {
    tile[r][c0 + j]      = f2bf(va[j]);
    tile[r][c0 + 4 + j]  = f2bf(vb[j]);
    tile[r][c0 + 8 + j]  = f2bf(vc[j]);
    tile[r][c0 + 12 + j] = f2bf(vd[j]);
  }
  __syncthreads();
  us8 o0, o1;
  #pragma unroll
  for (int j = 0; j < 8; j++) { o0[j] = tile[c0 + j][r]; o1[j] = tile[c0 + 8 + j][r]; }
  u16* op = Wt + (size_t)(n0 + r) * 1024 + k0 + c0;
  *(us8*)op       = o0;
  *(us8*)(op + 8) = o1;
}

// ======= gemm1: dbuf gl_lds MFMA GEMM, A[M][K] * Bt[N][K]^T -> C[M][N] bf16 =======
// 128x128 tile, BK=64, 256 thr (4 waves 2x2). Double-buffered linear LDS
// (2 x (A 16KB + B 16KB) = 64KB, 2 blocks/CU). Per K-tile: issue next-tile
// gl_lds FIRST, then ds_read+MFMA current, then ONE __syncthreads (drains
// vmcnt+lgkmcnt): prefetch latency hides under the 32 MFMAs.
// T2 chunk swizzle via pre-swizzled global source (rule #21):
//   stage: lane chunk (l&7)^((l>>3)&7); read: chunk (kh*4+g)^(fr&7).
__global__ __launch_bounds__(256)
void k_gemm_db(const u16* __restrict__ A, const u16* __restrict__ Bt,
               u16* __restrict__ C, int M, int N, int K) {
  __shared__ __align__(16) u16 LB[2][2][8192];   // [buf][A/B][128*64]
  const int bm0 = blockIdx.y * 128;
  const int bn0 = blockIdx.x * 128;
  const int tid = threadIdx.x;
  const int wave = tid >> 6;
  const int lane = tid & 63;
  const int fr = lane & 15;
  const int g  = lane >> 4;
  const int wr = wave >> 1, wc = wave & 1;
  const int srow = lane >> 3;                    // 0..7 within 8-row group
  const int schunk = (lane & 7) ^ (srow & 7);    // swizzled source chunk
  const u16* Asrc = A  + (size_t)(bm0 + wave * 32 + srow) * K + schunk * 8;
  const u16* Bsrc = Bt + (size_t)(bn0 + wave * 32 + srow) * K + schunk * 8;
  f4 acc[4][4] = {};
  const int KT = K >> 6;

  // prologue: stage tile 0 into buf 0
  #pragma unroll
  for (int i = 0; i < 4; i++) {
    gl16(Asrc + (size_t)(i * 8) * K, &LB[0][0][(wave * 32 + i * 8) * 64]);
    gl16(Bsrc + (size_t)(i * 8) * K, &LB[0][1][(wave * 32 + i * 8) * 64]);
  }
  __syncthreads();

  int cur = 0;
  for (int kt = 0; kt < KT; kt++) {
    if (kt + 1 < KT) {
      const size_t go = (size_t)(kt + 1) * 64;
      #pragma unroll
      for (int i = 0; i < 4; i++) {
        gl16(Asrc + (size_t)(i * 8) * K + go, &LB[cur ^ 1][0][(wave * 32 + i * 8) * 64]);
        gl16(Bsrc + (size_t)(i * 8) * K + go, &LB[cur ^ 1][1][(wave * 32 + i * 8) * 64]);
      }
    }
    __builtin_amdgcn_sched_barrier(0);   // keep prefetch issue ahead of compute
    const u16* As = &LB[cur][0][0];
    const u16* Bs = &LB[cur][1][0];
    #pragma unroll
    for (int kh = 0; kh < 2; kh++) {
      sh8 af[4], bfv[4];
      const int ch = ((kh * 4 + g) ^ (fr & 7)) * 8;
      #pragma unroll
      for (int mi = 0; mi < 4; mi++)
        af[mi] = *(const sh8*)&As[(wr * 64 + mi * 16 + fr) * 64 + ch];
      #pragma unroll
      for (int ni = 0; ni < 4; ni++)
        bfv[ni] = *(const sh8*)&Bs[(wc * 64 + ni * 16 + fr) * 64 + ch];
      #pragma unroll
      for (int mi = 0; mi < 4; mi++)
        #pragma unroll
        for (int ni = 0; ni < 4; ni++)
          acc[mi][ni] = __builtin_amdgcn_mfma_f32_16x16x32_bf16(af[mi], bfv[ni], acc[mi][ni], 0, 0, 0);
    }
    __syncthreads();   // drains vmcnt (prefetch landed) + lgkmcnt, fences buffers
    cur ^= 1;
  }

  const int rbase = bm0 + wr * 64 + g * 4;
  const int cbase = bn0 + wc * 64 + fr;
  #pragma unroll
  for (int mi = 0; mi < 4; mi++)
    #pragma unroll
    for (int ni = 0; ni < 4; ni++)
      #pragma unroll
      for (int r = 0; r < 4; r++)
        C[(size_t)(rbase + mi * 16 + r) * N + cbase + ni * 16] = f2bf(acc[mi][ni][r]);
}

// ---- bf16 MFMA GEMM (round-2 known-good), used for gemm2 ----
template<bool OUT_BF16>
__global__ __launch_bounds__(256, 4)
void k_gemm_bt(const u16* __restrict__ A, const u16* __restrict__ Bt,
               void* __restrict__ Cout, int M, int N, int K) {
  constexpr int LDT = 72;
  __shared__ __align__(16) u16 As[128 * LDT];
  __shared__ __align__(16) u16 Bs[128 * LDT];
  const int bm0 = blockIdx.y * 128;
  const int bn0 = blockIdx.x * 128;
  const int t = threadIdx.x;
  const int lane = t & 63;
  const int wave = t >> 6;
  const int wr = wave >> 1, wc = wave & 1;
  f4 acc[4][4] = {};
  const int sr = t >> 1;
  const int sc = (t & 1) * 32;
  const u16* Ap = A + (size_t)(bm0 + sr) * K + sc;
  const u16* Bp = Bt + (size_t)(bn0 + sr) * K + sc;
  u16* AsW = &As[sr * LDT + sc];
  u16* BsW = &Bs[sr * LDT + sc];
  const int fr = lane & 15;
  const int ko = (lane >> 4) * 8;
  for (int kt = 0; kt < K; kt += 64) {
    sh8 a0 = *(const sh8*)(Ap + kt);
    sh8 a1 = *(const sh8*)(Ap + kt + 8);
    sh8 a2 = *(const sh8*)(Ap + kt + 16);
    sh8 a3 = *(const sh8*)(Ap + kt + 24);
    sh8 b0 = *(const sh8*)(Bp + kt);
    sh8 b1 = *(const sh8*)(Bp + kt + 8);
    sh8 b2 = *(const sh8*)(Bp + kt + 16);
    sh8 b3 = *(const sh8*)(Bp + kt + 24);
    __syncthreads();
    *(sh8*)(AsW) = a0; *(sh8*)(AsW + 8) = a1; *(sh8*)(AsW + 16) = a2; *(sh8*)(AsW + 24) = a3;
    *(sh8*)(BsW) = b0; *(sh8*)(BsW + 8) = b1; *(sh8*)(BsW + 16) = b2; *(sh8*)(BsW + 24) = b3;
    __syncthreads();
    #pragma unroll
    for (int kh = 0; kh < 2; kh++) {
      sh8 af[4], bfv[4];
      const int kofs = kh * 32 + ko;
      #pragma unroll
      for (int mi = 0; mi < 4; mi++)
        af[mi] = *(const sh8*)&As[(wr * 64 + mi * 16 + fr) * LDT + kofs];
      #pragma unroll
      for (int ni = 0; ni < 4; ni++)
        bfv[ni] = *(const sh8*)&Bs[(wc * 64 + ni * 16 + fr) * LDT + kofs];
      #pragma unroll
      for (int mi = 0; mi < 4; mi++)
        #pragma unroll
        for (int ni = 0; ni < 4; ni++)
          acc[mi][ni] = __builtin_amdgcn_mfma_f32_16x16x32_bf16(af[mi], bfv[ni], acc[mi][ni], 0, 0, 0);
    }
  }
  const int rbase = bm0 + wr * 64 + (lane >> 4) * 4;
  const int cbase = bn0 + wc * 64 + fr;
  #pragma unroll
  for (int mi = 0; mi < 4; mi++)
    #pragma unroll
    for (int ni = 0; ni < 4; ni++)
      #pragma unroll
      for (int r = 0; r < 4; r++) {
        const size_t off = (size_t)(rbase + mi * 16 + r) * N + (cbase + ni * 16);
        if constexpr (OUT_BF16) ((u16*)Cout)[off] = f2bf(acc[mi][ni][r]);
        else                    ((float*)Cout)[off] = acc[mi][ni][r];
      }
}

// ---- mean-pool kc/vc -> kpb[bh][128][64] bf16, vpT[bh][64][128] bf16 (pad zeroed) ----
__global__ __launch_bounds__(64)
void k_pool(const u16* __restrict__ proj, u16* __restrict__ kpb, u16* __restrict__ vpT) {
  const int j = blockIdx.x;    // 0..127 (127 = zero pad)
  const int bh = blockIdx.y;   // 0..31
  const int b = bh >> 4, h = bh & 15;
  const int d = threadIdx.x;
  u16 kout = 0, vout = 0;
  if (j < 127) {
    const size_t base = (size_t)(b * 2048 + j * 16) * 5120;
    const size_t kcol = 3072 + h * 64 + d;
    const size_t vcol = 4096 + h * 64 + d;
    float ks = 0.f, vs = 0.f;
    #pragma unroll 4
    for (int r = 0; r < 32; r++) {
      const size_t off = base + (size_t)r * 5120;
      ks += bf2f(proj[off + kcol]);
      vs += bf2f(proj[off + vcol]);
    }
    kout = f2bf(ks * (1.f / 32.f));
    vout = f2bf(vs * (1.f / 32.f));
  }
  kpb[((size_t)bh * 128 + j) * 64 + d] = kout;
  vpT[((size_t)bh * 64 + d) * 128 + j] = vout;
}

// ---- transpose vl: proj cols [2048,3072) -> vlT[bh][64 d][2048 t] bf16 ----
__global__ __launch_bounds__(256)
void k_vt(const u16* __restrict__ proj, u16* __restrict__ vlT) {
  __shared__ u16 tile[64][72];
  const int tt = blockIdx.x;   // 0..31 token tile
  const int bh = blockIdx.y;   // 0..31
  const int b = bh >> 4, h = bh & 15;
  const int t = threadIdx.x;
  const int r = t >> 2;          // 0..63
  const int c0 = (t & 3) * 16;
  const u16* sp = proj + (size_t)(b * 2048 + tt * 64 + r) * 5120 + 2048 + h * 64 + c0;
  us8 v0 = *(const us8*)sp;
  us8 v1 = *(const us8*)(sp + 8);
  #pragma unroll
  for (int jj = 0; jj < 8; jj++) { tile[r][c0 + jj] = v0[jj]; tile[r][c0 + 8 + jj] = v1[jj]; }
  __syncthreads();
  u16* op = vlT + ((size_t)bh * 64 + r) * 2048 + tt * 64 + c0;
  #pragma unroll
  for (int jj = 0; jj < 16; jj++) op[jj] = tile[c0 + jj][r];
}

// -------- attention LOCAL phase: writes y_local (pre-normalized) to yb --------
__global__ __launch_bounds__(256)
void k_attn_local(const u16* __restrict__ proj, const u16* __restrict__ vlT,
                  u16* __restrict__ yb) {
  __shared__ __align__(16) u16 SB[26688];   // 53376 B -> 3 blocks/CU
  const int qt = blockIdx.x;          // 0..31
  const int bh = blockIdx.y;          // 0..31
  const int b = bh >> 4, h = bh & 15;
  const int tid = threadIdx.x;
  const int wave = tid >> 6;
  const int lane = tid & 63;
  const int fr = lane & 15;
  const int g  = lane >> 4;
  const int ko = g * 8;
  const int q0 = qt * 64;
  const int wq0 = q0 + wave * 16;
  const int i_abs = wq0 + fr;

  const u16* prow = proj + (size_t)(b * 2048) * 5120;
  const u16* klb = prow + 1024 + h * 64;
  const u16* vltb = vlT + (size_t)bh * 64 * 2048;

  #pragma unroll
  for (int it = 0; it < 7; it++) {
    const int inst = it * 4 + wave;
    if (inst < 27) {
      const int c = inst * 64 + lane;
      const int row = c / 9;
      const int sl = c - row * 9;
      int jg = q0 - 128 + row; if (jg < 0) jg = 0;
      gl16(klb + (size_t)jg * 5120 + (sl & 7) * 8, &SB[inst * 512]);
    }
  }
  #pragma unroll
  for (int it = 0; it < 7; it++) {
    const int inst = it * 4 + wave;
    if (inst < 25) {
      const int c = inst * 64 + lane;
      const int row = c / 25;
      const int sl = c - row * 25;
      int tc = q0 - 128 + (sl < 24 ? sl : 0) * 8; if (tc < 0) tc = 0;
      gl16(vltb + (size_t)row * 2048 + tc, &SB[13824 + inst * 512]);
    }
  }
  const sh8 bq0 = *(const sh8*)(prow + (size_t)i_abs * 5120 + h * 64 + ko);
  const sh8 bq1 = *(const sh8*)(prow + (size_t)i_abs * 5120 + h * 64 + 32 + ko);
  __syncthreads();   // barrier 1: stages resident

  f4 st[9];
  #pragma unroll
  for (int f = 0; f < 9; f++) st[f] = f4{0.f, 0.f, 0.f, 0.f};
  #pragma unroll
  for (int kh = 0; kh < 2; kh++) {
    const sh8 bq = kh ? bq1 : bq0;
    #pragma unroll
    for (int f = 0; f < 9; f++) {
      sh8 ak = *(const sh8*)&SB[(wave * 16 + f * 16 + fr) * 72 + kh * 32 + ko];
      st[f] = __builtin_amdgcn_mfma_f32_16x16x32_bf16(ak, bq, st[f], 0, 0, 0);
    }
  }
  const int klo = 128 - wq0;
  float m = -1e30f;
  #pragma unroll
  for (int f = 0; f < 9; f++)
    #pragma unroll
    for (int r = 0; r < 4; r++) {
      const int kk = f * 16 + g * 4 + r;
      const bool ok = (kk > fr) && (kk <= fr + 128) && (kk >= klo);
      const float v = ok ? st[f][r] * 0.125f : -1e30f;
      st[f][r] = v; m = fmaxf(m, v);
    }
  m = fmaxf(m, __shfl_xor(m, 16));
  m = fmaxf(m, __shfl_xor(m, 32));
  float l = 0.f;
  #pragma unroll
  for (int f = 0; f < 9; f++)
    #pragma unroll
    for (int r = 0; r < 4; r++) {
      const float p = __expf(st[f][r] - m);
      st[f][r] = p; l += p;
    }
  l += __shfl_xor(l, 16);
  l += __shfl_xor(l, 32);
  const float inv = 1.f / l;      // l>0: key j=i always allowed

  __syncthreads();   // barrier 2: KL reads done; region becomes P

  u16* Pw = &SB[wave * 2688];     // [16][168]
  #pragma unroll
  for (int f = 0; f < 9; f++)
    *(ui2*)&Pw[fr * 168 + f * 16 + g * 4] =
        pk4(st[f][0] * inv, st[f][1] * inv, st[f][2] * inv, st[f][3] * inv);
  *(ui2*)&Pw[fr * 168 + 144 + g * 4] = ui2{0u, 0u};   // zero pad kk [144,160)

  f4 yacc[4];
  #pragma unroll
  for (int ni = 0; ni < 4; ni++) yacc[ni] = f4{0.f, 0.f, 0.f, 0.f};
  #pragma unroll
  for (int ks = 0; ks < 5; ks++) {
    sh8 pa = *(const sh8*)&Pw[fr * 168 + ks * 32 + ko];
    const int col = wave * 16 + ks * 32 + ko;          // < 208, pad-safe
    #pragma unroll
    for (int ni = 0; ni < 4; ni++) {
      sh8 vb = *(const sh8*)&SB[13824 + (ni * 16 + fr) * 200 + col];
      yacc[ni] = __builtin_amdgcn_mfma_f32_16x16x32_bf16(pa, vb, yacc[ni], 0, 0, 0);
    }
  }

  #pragma unroll
  for (int ni = 0; ni < 4; ni++)
    #pragma unroll
    for (int r = 0; r < 4; r++)
      Pw[(4 * g + r) * 72 + ni * 16 + fr] = f2bf(yacc[ni][r]);
  {
    const int row = lane >> 2;
    const int c0 = (lane & 3) * 16;
    u16* gy = yb + (size_t)(b * 2048 + wq0 + row) * 1024 + h * 64 + c0;
    *(us8*)gy       = *(const us8*)&Pw[row * 72 + c0];
    *(us8*)(gy + 8) = *(const us8*)&Pw[row * 72 + c0 + 8];
  }
}

// -------- attention COMPRESSED phase: yb += y_comp (runs after local) --------
__global__ __launch_bounds__(256)
void k_attn_comp(const u16* __restrict__ proj, const u16* __restrict__ kpb,
                 const u16* __restrict__ vpT, u16* __restrict__ yb) {
  __shared__ __align__(16) u16 SB[17920];   // 35840 B -> 4 blocks/CU
  const int qt = blockIdx.x;
  const int bh = blockIdx.y;
  const int b = bh >> 4, h = bh & 15;
  const int tid = threadIdx.x;
  const int wave = tid >> 6;
  const int lane = tid & 63;
  const int fr = lane & 15;
  const int g  = lane >> 4;
  const int ko = g * 8;
  const int wq0 = qt * 64 + wave * 16;
  const int i_abs = wq0 + fr;

  const u16* prow = proj + (size_t)(b * 2048) * 5120;
  const u16* kpr = kpb + (size_t)bh * 8192;
  const u16* vptb = vpT + (size_t)bh * 8192;

  #pragma unroll
  for (int it = 0; it < 5; it++) {
    const int inst = it * 4 + wave;
    if (inst < 18) {
      const int c = inst * 64 + lane;
      const int row = c / 9;
      const int sl = c - row * 9;
      gl16(kpr + (size_t)row * 64 + (sl & 7) * 8, &SB[inst * 512]);
    }
  }
  #pragma unroll
  for (int it = 0; it < 5; it++) {
    const int inst = it * 4 + wave;
    if (inst < 17) {
      const int c = inst * 64 + lane;
      const int row = c / 17;
      const int sl = c - row * 17;
      gl16(vptb + (size_t)row * 128 + (sl & 15) * 8, &SB[9216 + inst * 512]);
    }
  }
  const sh8 bq0 = *(const sh8*)(prow + (size_t)i_abs * 5120 + h * 64 + ko);
  const sh8 bq1 = *(const sh8*)(prow + (size_t)i_abs * 5120 + h * 64 + 32 + ko);
  const int yrow = lane >> 2;
  const int yc0 = (lane & 3) * 16;
  u16* gy = yb + (size_t)(b * 2048 + wq0 + yrow) * 1024 + h * 64 + yc0;
  const us8 yold0 = *(const us8*)gy;
  const us8 yold1 = *(const us8*)(gy + 8);
  __syncthreads();   // barrier 1

  const int nf = ((wq0 + 15) >> 8) + 1;   // 1..8, wave-uniform
  f4 sc[8];
  #pragma unroll
  for (int f = 0; f < 8; f++) sc[f] = f4{0.f, 0.f, 0.f, 0.f};
  #pragma unroll
  for (int kh = 0; kh < 2; kh++) {
    const sh8 bq = kh ? bq1 : bq0;
    #pragma unroll
    for (int f = 0; f < 8; f++)
      if (f < nf) {
        sh8 ak = *(const sh8*)&SB[(f * 16 + fr) * 72 + kh * 32 + ko];
        sc[f] = __builtin_amdgcn_mfma_f32_16x16x32_bf16(ak, bq, sc[f], 0, 0, 0);
      }
  }
  float m2 = -1e30f;
  #pragma unroll
  for (int f = 0; f < 8; f++)
    #pragma unroll
    for (int r = 0; r < 4; r++) {
      const int jj = f * 16 + g * 4 + r;
      const bool ok = (jj <= 126) && (16 * jj <= i_abs);
      const float v = ok ? sc[f][r] * 0.125f : -1e30f;
      sc[f][r] = v; m2 = fmaxf(m2, v);
    }
  m2 = fmaxf(m2, __shfl_xor(m2, 16));
  m2 = fmaxf(m2, __shfl_xor(m2, 32));
  float l2 = 0.f;
  #pragma unroll
  for (int f = 0; f < 8; f++)
    #pragma unroll
    for (int r = 0; r < 4; r++) {
      const float p = __expf(sc[f][r] - m2);
      sc[f][r] = p; l2 += p;
    }
  l2 += __shfl_xor(l2, 16);
  l2 += __shfl_xor(l2, 32);
  const float inv2 = 1.f / l2;    // l2>0: block 0 allowed for every i

  __syncthreads();   // barrier 2: KC reads done; region becomes P

  u16* Pw = &SB[wave * 2176];     // [16][136]
  #pragma unroll
  for (int f = 0; f < 8; f++)
    if (f < nf)
      *(ui2*)&Pw[fr * 136 + f * 16 + g * 4] =
          pk4(sc[f][0] * inv2, sc[f][1] * inv2, sc[f][2] * inv2, sc[f][3] * inv2);
  if (nf & 1)
    *(ui2*)&Pw[fr * 136 + nf * 16 + g * 4] = ui2{0u, 0u};   // pad odd frag

  f4 yacc[4];
  #pragma unroll
  for (int ni = 0; ni < 4; ni++) yacc[ni] = f4{0.f, 0.f, 0.f, 0.f};
  const int nks = (nf + 1) >> 1;
  #pragma unroll
  for (int ks = 0; ks < 4; ks++)
    if (ks < nks) {
      sh8 pa = *(const sh8*)&Pw[fr * 136 + ks * 32 + ko];
      #pragma unroll
      for (int ni = 0; ni < 4; ni++) {
        sh8 vb = *(const sh8*)&SB[9216 + (ni * 16 + fr) * 136 + ks * 32 + ko];
        yacc[ni] = __builtin_amdgcn_mfma_f32_16x16x32_bf16(pa, vb, yacc[ni], 0, 0, 0);
      }
    }

  #pragma unroll
  for (int ni = 0; ni < 4; ni++)
    #pragma unroll
    for (int r = 0; r < 4; r++)
      Pw[(4 * g + r) * 72 + ni * 16 + fr] = f2bf(yacc[ni][r]);
  {
    const us8 yc = *(const us8*)&Pw[yrow * 72 + yc0];
    const us8 yc2 = *(const us8*)&Pw[yrow * 72 + yc0 + 8];
    us8 o0, o1;
    #pragma unroll
    for (int jj = 0; jj < 8; jj++) {
      o0[jj] = f2bf(bf2f(yold0[jj]) + bf2f(yc[jj]));
      o1[jj] = f2bf(bf2f(yold1[jj]) + bf2f(yc2[jj]));
    }
    *(us8*)gy       = o0;
    *(us8*)(gy + 8) = o1;
  }
}

extern "C" void kernel_launch(void* const* d_in, const int* in_sizes, int n_in,
                              void* d_out, int out_size, void* d_ws, size_t ws_size,
                              hipStream_t stream) {
  const float* x  = (const float*)d_in[0];
  const float* Wq = (const float*)d_in[1];
  const float* Wl = (const float*)d_in[2];
  const float* Wc = (const float*)d_in[3];
  const float* Wo = (const float*)d_in[4];
  // dkc/dvc unused: n_def == 0 at T=2048.
  float* out = (float*)d_out;
  char* ws = (char*)d_ws;
  // workspace (72.4 MB): vlT aliases xb (xb dead after gemm1)
  u16* xb   = (u16*)(ws);                       //  8 MB  x bf16 [4096][1024]
  u16* vlT  = (u16*)(ws);                       //  8 MB  vl^T bf16 [32][64][2048] (after gemm1)
  u16* Wt   = (u16*)(ws + 8388608);             // 12 MB  weights^T bf16 [6144][1024]
  u16* proj = (u16*)(ws + 20971520);            // 40 MB  [4096][5120] q|kl|vl|kc|vc
  u16* kpb  = (u16*)(ws + 62914560);            // 512 KB pooled K bf16 [32][128][64]
  u16* vpT  = (u16*)(ws + 63438848);            // 512 KB pooled V^T bf16 [32][64][128]
  u16* yb   = (u16*)(ws + 63963136);            //  8 MB  y bf16 [4096][1024]

  k_cvt_bf16<<<2048, 256, 0, stream>>>(x, xb, 4194304 / 8);
  k_prep_w<<<dim3(96, 16), 256, 0, stream>>>(Wq, Wl, Wc, Wo, Wt);
  k_gemm_db<<<dim3(40, 32), 256, 0, stream>>>(xb, Wt, proj, 4096, 5120, 1024);
  k_pool<<<dim3(128, 32), 64, 0, stream>>>(proj, kpb, vpT);
  k_vt<<<dim3(32, 32), 256, 0, stream>>>(proj, vlT);
  k_attn_local<<<dim3(32, 32), 256, 0, stream>>>(proj, vlT, yb);
  k_attn_comp<<<dim3(32, 32), 256, 0, stream>>>(proj, kpb, vpT, yb);
  k_gemm_bt<false><<<dim3(8, 32), 256, 0, stream>>>(yb, Wt + (size_t)5120 * 1024, out, 4096, 1024, 1024);
}

// Round 9
// 141.207 us; speedup vs baseline: 1.2081x; 1.0011x over previous
//
#include <hip/hip_runtime.h>

typedef unsigned short u16;
typedef unsigned int u32;
typedef __attribute__((ext_vector_type(8))) short sh8;           // 8 bf16 (4 VGPR)
typedef __attribute__((ext_vector_type(8))) unsigned short us8;
typedef __attribute__((ext_vector_type(2))) unsigned int ui2;
typedef __attribute__((ext_vector_type(4))) float f4;

__device__ __forceinline__ float bf2f(u16 u) {
  union { unsigned u; float f; } v; v.u = ((unsigned)u) << 16; return v.f;
}
__device__ __forceinline__ u16 f2bf(float f) {
  union { float f; unsigned u; } v; v.f = f;
  unsigned r = v.u + 0x7fffu + ((v.u >> 16) & 1u);   // RNE, inputs finite
  return (u16)(r >> 16);
}
// pack 4 f32 -> 4 bf16 (RNE) in 2 insts
__device__ __forceinline__ ui2 pk4(float a, float b, float c, float d) {
  u32 lo, hi;
  asm("v_cvt_pk_bf16_f32 %0, %1, %2" : "=v"(lo) : "v"(a), "v"(b));
  asm("v_cvt_pk_bf16_f32 %0, %1, %2" : "=v"(hi) : "v"(c), "v"(d));
  ui2 r; r[0] = lo; r[1] = hi; return r;
}
// async global->LDS, 16B per lane; dest = wave-uniform base + lane*16
__device__ __forceinline__ void gl16(const void* g, void* l) {
  __builtin_amdgcn_global_load_lds(
      (const __attribute__((address_space(1))) unsigned int*)g,
      (__attribute__((address_space(3))) unsigned int*)l, 16, 0, 0);
}

// ------- fused: f32->bf16 cvt (bx<2048) | weight concat+transpose (bx>=2048) -------
__global__ __launch_bounds__(256)
void k_prep(const float* __restrict__ x, const float* __restrict__ Wq,
            const float* __restrict__ Wl, const float* __restrict__ Wc,
            const float* __restrict__ Wo, u16* __restrict__ xb,
            u16* __restrict__ Wt) {
  __shared__ u16 tile[64][65];
  const int bx = blockIdx.x;
  const int t = threadIdx.x;
  if (bx < 2048) {
    const int idx = bx * 256 + t;            // < 524288 = 4194304/8
    const f4* p = (const f4*)x + (size_t)idx * 2;
    f4 a = p[0], b = p[1];
    us8 o;
    o[0] = f2bf(a[0]); o[1] = f2bf(a[1]); o[2] = f2bf(a[2]); o[3] = f2bf(a[3]);
    o[4] = f2bf(b[0]); o[5] = f2bf(b[1]); o[6] = f2bf(b[2]); o[7] = f2bf(b[3]);
    ((us8*)xb)[idx] = o;
    return;
  }
  const int id = bx - 2048;                  // 0..1535
  const int n0 = (id % 96) * 64;
  const int k0 = (id / 96) * 64;
  const float* src; int ld, col0;
  if (n0 < 1024)      { src = Wq; ld = 1024; col0 = n0; }
  else if (n0 < 3072) { src = Wl; ld = 2048; col0 = n0 - 1024; }
  else if (n0 < 5120) { src = Wc; ld = 2048; col0 = n0 - 3072; }
  else                { src = Wo; ld = 1024; col0 = n0 - 5120; }
  const int r = t >> 2;          // 0..63
  const int c0 = (t & 3) * 16;   // 0,16,32,48
  const f4* sp = (const f4*)(src + (size_t)(k0 + r) * ld + col0 + c0);
  const f4 va = sp[0], vb = sp[1], vc = sp[2], vd = sp[3];
  #pragma unroll
  for (int j = 0; j < 4; j++) {
    tile[r][c0 + j]      = f2bf(va[j]);
    tile[r][c0 + 4 + j]  = f2bf(vb[j]);
    tile[r][c0 + 8 + j]  = f2bf(vc[j]);
    tile[r][c0 + 12 + j] = f2bf(vd[j]);
  }
  __syncthreads();
  us8 o0, o1;
  #pragma unroll
  for (int j = 0; j < 8; j++) { o0[j] = tile[c0 + j][r]; o1[j] = tile[c0 + 8 + j][r]; }
  u16* op = Wt + (size_t)(n0 + r) * 1024 + k0 + c0;
  *(us8*)op       = o0;
  *(us8*)(op + 8) = o1;
}

// ======= gemm1: 3-slot counted-vmcnt pipeline, A[M][K] * Bt[N][K]^T -> C bf16 =======
// BM=128, BN=256, BK=64, 8 waves (512 thr). Wave (wr=w>>2, wc=w&3) owns 64x64.
// LDS: 3 slots x (A[128][64] + B[256][64]) = 144 KB, 1 block/CU (2 waves/SIMD).
// Iter kt: STAGE(kt+2) -> compute kt -> vmcnt(6) (retires kt+1, issued one full
// iteration earlier => pre-satisfied; never 0 until tail) -> raw s_barrier.
// Slot (kt+2)%3's previous reader = tile kt-1, closed >=1 barrier earlier.
// Swizzle (r8-verified): source chunk (c&7)^(row&7); read chunk (kh*4+g)^(fr&7).
__global__ __launch_bounds__(512)
void k_gemm3s(const u16* __restrict__ A, const u16* __restrict__ Bt,
              u16* __restrict__ C, int M, int N, int K) {
  constexpr int ASZ = 128 * 64;              // u16
  constexpr int TSZ = ASZ + 256 * 64;        // 24576 u16 = 48 KB
  __shared__ __align__(16) u16 LB[3 * TSZ];  // 147,456 B
  const int nwg = gridDim.x;
  int wg = blockIdx.x;
  wg = (wg & 7) * (nwg >> 3) + (wg >> 3);    // XCD grouping (nwg % 8 == 0)
  const int ntn = N >> 8;                    // 256-wide n tiles
  const int bm0 = (wg / ntn) << 7;
  const int bn0 = (wg % ntn) << 8;
  const int tid = threadIdx.x;
  const int wave = tid >> 6;
  const int lane = tid & 63;
  const int fr = lane & 15;
  const int g  = lane >> 4;
  const int wr = wave >> 2;                  // 0..1 (M)
  const int wc = wave & 3;                   // 0..3 (N)
  const int KT = K >> 6;
  f4 acc[4][4] = {};

  auto STAGE = [&](int t) {
    const int s = t - (t / 3) * 3;
    const size_t kofs = (size_t)t << 6;
    #pragma unroll
    for (int i = 0; i < 6; i++) {
      const int gbase = i * 512 + wave * 64;    // wave-uniform
      const int gc = gbase + lane;
      if (gbase < 1024) {                       // A: insts 0,1 (rows 0..127)
        const int row = gc >> 3;
        const int slc = (gc & 7) ^ (row & 7);
        gl16(A + (size_t)(bm0 + row) * K + kofs + slc * 8,
             &LB[s * TSZ + gbase * 8]);
      } else {                                  // B: insts 2..5 (rows 0..255)
        const int gb = gc - 1024;
        const int row = gb >> 3;
        const int slc = (gb & 7) ^ (row & 7);
        gl16(Bt + (size_t)(bn0 + row) * K + kofs + slc * 8,
             &LB[s * TSZ + ASZ + (gbase - 1024) * 8]);
      }
    }
  };

  STAGE(0); STAGE(1);
  __builtin_amdgcn_sched_barrier(0);
  asm volatile("s_waitcnt vmcnt(6)" ::: "memory");   // tile 0 resident
  __builtin_amdgcn_s_barrier();
  __builtin_amdgcn_sched_barrier(0);

  for (int kt = 0; kt < KT; kt++) {
    const int s = kt - (kt / 3) * 3;
    const bool pf = (kt + 2) < KT;
    if (pf) STAGE(kt + 2);
    __builtin_amdgcn_sched_barrier(0);             // issue stage before compute
    const u16* As = &LB[s * TSZ];
    const u16* Bs = &LB[s * TSZ + ASZ];
    #pragma unroll
    for (int kh = 0; kh < 2; kh++) {
      sh8 af[4], bfv[4];
      const int ch = ((kh * 4 + g) ^ (fr & 7)) * 8;
      #pragma unroll
      for (int mi = 0; mi < 4; mi++)
        af[mi] = *(const sh8*)&As[(wr * 64 + mi * 16 + fr) * 64 + ch];
      #pragma unroll
      for (int ni = 0; ni < 4; ni++)
        bfv[ni] = *(const sh8*)&Bs[(wc * 64 + ni * 16 + fr) * 64 + ch];
      #pragma unroll
      for (int mi = 0; mi < 4; mi++)
        #pragma unroll
        for (int ni = 0; ni < 4; ni++)
          acc[mi][ni] = __builtin_amdgcn_mfma_f32_16x16x32_bf16(af[mi], bfv[ni], acc[mi][ni], 0, 0, 0);
    }
    __builtin_amdgcn_sched_barrier(0);
    if (pf) asm volatile("s_waitcnt vmcnt(6)" ::: "memory");   // retire kt+1
    else    asm volatile("s_waitcnt vmcnt(0)" ::: "memory");   // tail drain
    __builtin_amdgcn_s_barrier();
    __builtin_amdgcn_sched_barrier(0);
  }

  const int rb = bm0 + wr * 64 + g * 4;
  const int cb = bn0 + wc * 64 + fr;
  #pragma unroll
  for (int mi = 0; mi < 4; mi++)
    #pragma unroll
    for (int ni = 0; ni < 4; ni++)
      #pragma unroll
      for (int r = 0; r < 4; r++)
        C[(size_t)(rb + mi * 16 + r) * N + cb + ni * 16] = f2bf(acc[mi][ni][r]);
}

// ======= gemm2: dbuf gl_lds MFMA GEMM (r8-verified), templated output =======
template<bool OUT_BF16>
__global__ __launch_bounds__(256)
void k_gemm_db(const u16* __restrict__ A, const u16* __restrict__ Bt,
               void* __restrict__ Cout, int M, int N, int K) {
  __shared__ __align__(16) u16 LB[2][2][8192];   // [buf][A/B][128*64]
  const int bm0 = blockIdx.y * 128;
  const int bn0 = blockIdx.x * 128;
  const int tid = threadIdx.x;
  const int wave = tid >> 6;
  const int lane = tid & 63;
  const int fr = lane & 15;
  const int g  = lane >> 4;
  const int wr = wave >> 1, wc = wave & 1;
  const int srow = lane >> 3;
  const int schunk = (lane & 7) ^ (srow & 7);
  const u16* Asrc = A  + (size_t)(bm0 + wave * 32 + srow) * K + schunk * 8;
  const u16* Bsrc = Bt + (size_t)(bn0 + wave * 32 + srow) * K + schunk * 8;
  f4 acc[4][4] = {};
  const int KT = K >> 6;

  #pragma unroll
  for (int i = 0; i < 4; i++) {
    gl16(Asrc + (size_t)(i * 8) * K, &LB[0][0][(wave * 32 + i * 8) * 64]);
    gl16(Bsrc + (size_t)(i * 8) * K, &LB[0][1][(wave * 32 + i * 8) * 64]);
  }
  __syncthreads();

  int cur = 0;
  for (int kt = 0; kt < KT; kt++) {
    if (kt + 1 < KT) {
      const size_t go = (size_t)(kt + 1) * 64;
      #pragma unroll
      for (int i = 0; i < 4; i++) {
        gl16(Asrc + (size_t)(i * 8) * K + go, &LB[cur ^ 1][0][(wave * 32 + i * 8) * 64]);
        gl16(Bsrc + (size_t)(i * 8) * K + go, &LB[cur ^ 1][1][(wave * 32 + i * 8) * 64]);
      }
    }
    __builtin_amdgcn_sched_barrier(0);
    const u16* As = &LB[cur][0][0];
    const u16* Bs = &LB[cur][1][0];
    #pragma unroll
    for (int kh = 0; kh < 2; kh++) {
      sh8 af[4], bfv[4];
      const int ch = ((kh * 4 + g) ^ (fr & 7)) * 8;
      #pragma unroll
      for (int mi = 0; mi < 4; mi++)
        af[mi] = *(const sh8*)&As[(wr * 64 + mi * 16 + fr) * 64 + ch];
      #pragma unroll
      for (int ni = 0; ni < 4; ni++)
        bfv[ni] = *(const sh8*)&Bs[(wc * 64 + ni * 16 + fr) * 64 + ch];
      #pragma unroll
      for (int mi = 0; mi < 4; mi++)
        #pragma unroll
        for (int ni = 0; ni < 4; ni++)
          acc[mi][ni] = __builtin_amdgcn_mfma_f32_16x16x32_bf16(af[mi], bfv[ni], acc[mi][ni], 0, 0, 0);
    }
    __syncthreads();
    cur ^= 1;
  }

  const int rbase = bm0 + wr * 64 + g * 4;
  const int cbase = bn0 + wc * 64 + fr;
  #pragma unroll
  for (int mi = 0; mi < 4; mi++)
    #pragma unroll
    for (int ni = 0; ni < 4; ni++)
      #pragma unroll
      for (int r = 0; r < 4; r++) {
        const size_t off = (size_t)(rbase + mi * 16 + r) * N + (cbase + ni * 16);
        if constexpr (OUT_BF16) ((u16*)Cout)[off] = f2bf(acc[mi][ni][r]);
        else                    ((float*)Cout)[off] = acc[mi][ni][r];
      }
}

// ------- fused: mean-pool (bx<32, 4 windows/block) | vl transpose (bx>=32) -------
__global__ __launch_bounds__(256)
void k_poolvt(const u16* __restrict__ proj, u16* __restrict__ kpb,
              u16* __restrict__ vpT, u16* __restrict__ vlT) {
  __shared__ u16 tile[64][72];
  const int bx = blockIdx.x;
  const int bh = blockIdx.y;
  const int b = bh >> 4, h = bh & 15;
  const int t = threadIdx.x;
  if (bx < 32) {
    const int j = bx * 4 + (t >> 6);   // 0..127 (127 = zero pad)
    const int d = t & 63;
    u16 kout = 0, vout = 0;
    if (j < 127) {
      const size_t base = (size_t)(b * 2048 + j * 16) * 5120;
      const size_t kcol = 3072 + h * 64 + d;
      const size_t vcol = 4096 + h * 64 + d;
      float ks = 0.f, vs = 0.f;
      #pragma unroll 4
      for (int r = 0; r < 32; r++) {
        const size_t off = base + (size_t)r * 5120;
        ks += bf2f(proj[off + kcol]);
        vs += bf2f(proj[off + vcol]);
      }
      kout = f2bf(ks * (1.f / 32.f));
      vout = f2bf(vs * (1.f / 32.f));
    }
    kpb[((size_t)bh * 128 + j) * 64 + d] = kout;
    vpT[((size_t)bh * 64 + d) * 128 + j] = vout;
    return;
  }
  const int tt = bx - 32;              // 0..31 token tile
  const int r = t >> 2;                // 0..63
  const int c0 = (t & 3) * 16;
  const u16* sp = proj + (size_t)(b * 2048 + tt * 64 + r) * 5120 + 2048 + h * 64 + c0;
  us8 v0 = *(const us8*)sp;
  us8 v1 = *(const us8*)(sp + 8);
  #pragma unroll
  for (int jj = 0; jj < 8; jj++) { tile[r][c0 + jj] = v0[jj]; tile[r][c0 + 8 + jj] = v1[jj]; }
  __syncthreads();
  u16* op = vlT + ((size_t)bh * 64 + r) * 2048 + tt * 64 + c0;
  #pragma unroll
  for (int jj = 0; jj < 16; jj++) op[jj] = tile[c0 + jj][r];
}

// -------- attention LOCAL phase: writes y_local (pre-normalized) to yb --------
__global__ __launch_bounds__(256)
void k_attn_local(const u16* __restrict__ proj, const u16* __restrict__ vlT,
                  u16* __restrict__ yb) {
  __shared__ __align__(16) u16 SB[26688];   // 53376 B -> 3 blocks/CU
  const int qt = blockIdx.x;          // 0..31
  const int bh = blockIdx.y;          // 0..31
  const int b = bh >> 4, h = bh & 15;
  const int tid = threadIdx.x;
  const int wave = tid >> 6;
  const int lane = tid & 63;
  const int fr = lane & 15;
  const int g  = lane >> 4;
  const int ko = g * 8;
  const int q0 = qt * 64;
  const int wq0 = q0 + wave * 16;
  const int i_abs = wq0 + fr;

  const u16* prow = proj + (size_t)(b * 2048) * 5120;
  const u16* klb = prow + 1024 + h * 64;
  const u16* vltb = vlT + (size_t)bh * 64 * 2048;

  #pragma unroll
  for (int it = 0; it < 7; it++) {
    const int inst = it * 4 + wave;
    if (inst < 27) {
      const int c = inst * 64 + lane;
      const int row = c / 9;
      const int sl = c - row * 9;
      int jg = q0 - 128 + row; if (jg < 0) jg = 0;
      gl16(klb + (size_t)jg * 5120 + (sl & 7) * 8, &SB[inst * 512]);
    }
  }
  #pragma unroll
  for (int it = 0; it < 7; it++) {
    const int inst = it * 4 + wave;
    if (inst < 25) {
      const int c = inst * 64 + lane;
      const int row = c / 25;
      const int sl = c - row * 25;
      int tc = q0 - 128 + (sl < 24 ? sl : 0) * 8; if (tc < 0) tc = 0;
      gl16(vltb + (size_t)row * 2048 + tc, &SB[13824 + inst * 512]);
    }
  }
  const sh8 bq0 = *(const sh8*)(prow + (size_t)i_abs * 5120 + h * 64 + ko);
  const sh8 bq1 = *(const sh8*)(prow + (size_t)i_abs * 5120 + h * 64 + 32 + ko);
  __syncthreads();   // barrier 1: stages resident

  f4 st[9];
  #pragma unroll
  for (int f = 0; f < 9; f++) st[f] = f4{0.f, 0.f, 0.f, 0.f};
  #pragma unroll
  for (int kh = 0; kh < 2; kh++) {
    const sh8 bq = kh ? bq1 : bq0;
    #pragma unroll
    for (int f = 0; f < 9; f++) {
      sh8 ak = *(const sh8*)&SB[(wave * 16 + f * 16 + fr) * 72 + kh * 32 + ko];
      st[f] = __builtin_amdgcn_mfma_f32_16x16x32_bf16(ak, bq, st[f], 0, 0, 0);
    }
  }
  const int klo = 128 - wq0;
  float m = -1e30f;
  #pragma unroll
  for (int f = 0; f < 9; f++)
    #pragma unroll
    for (int r = 0; r < 4; r++) {
      const int kk = f * 16 + g * 4 + r;
      const bool ok = (kk > fr) && (kk <= fr + 128) && (kk >= klo);
      const float v = ok ? st[f][r] * 0.125f : -1e30f;
      st[f][r] = v; m = fmaxf(m, v);
    }
  m = fmaxf(m, __shfl_xor(m, 16));
  m = fmaxf(m, __shfl_xor(m, 32));
  float l = 0.f;
  #pragma unroll
  for (int f = 0; f < 9; f++)
    #pragma unroll
    for (int r = 0; r < 4; r++) {
      const float p = __expf(st[f][r] - m);
      st[f][r] = p; l += p;
    }
  l += __shfl_xor(l, 16);
  l += __shfl_xor(l, 32);
  const float inv = 1.f / l;      // l>0: key j=i always allowed

  __syncthreads();   // barrier 2: KL reads done; region becomes P

  u16* Pw = &SB[wave * 2688];     // [16][168]
  #pragma unroll
  for (int f = 0; f < 9; f++)
    *(ui2*)&Pw[fr * 168 + f * 16 + g * 4] =
        pk4(st[f][0] * inv, st[f][1] * inv, st[f][2] * inv, st[f][3] * inv);
  *(ui2*)&Pw[fr * 168 + 144 + g * 4] = ui2{0u, 0u};   // zero pad kk [144,160)

  f4 yacc[4];
  #pragma unroll
  for (int ni = 0; ni < 4; ni++) yacc[ni] = f4{0.f, 0.f, 0.f, 0.f};
  #pragma unroll
  for (int ks = 0; ks < 5; ks++) {
    sh8 pa = *(const sh8*)&Pw[fr * 168 + ks * 32 + ko];
    const int col = wave * 16 + ks * 32 + ko;          // < 208, pad-safe
    #pragma unroll
    for (int ni = 0; ni < 4; ni++) {
      sh8 vb = *(const sh8*)&SB[13824 + (ni * 16 + fr) * 200 + col];
      yacc[ni] = __builtin_amdgcn_mfma_f32_16x16x32_bf16(pa, vb, yacc[ni], 0, 0, 0);
    }
  }

  #pragma unroll
  for (int ni = 0; ni < 4; ni++)
    #pragma unroll
    for (int r = 0; r < 4; r++)
      Pw[(4 * g + r) * 72 + ni * 16 + fr] = f2bf(yacc[ni][r]);
  {
    const int row = lane >> 2;
    const int c0 = (lane & 3) * 16;
    u16* gy = yb + (size_t)(b * 2048 + wq0 + row) * 1024 + h * 64 + c0;
    *(us8*)gy       = *(const us8*)&Pw[row * 72 + c0];
    *(us8*)(gy + 8) = *(const us8*)&Pw[row * 72 + c0 + 8];
  }
}

// -------- attention COMPRESSED phase: yb += y_comp (runs after local) --------
__global__ __launch_bounds__(256)
void k_attn_comp(const u16* __restrict__ proj, const u16* __restrict__ kpb,
                 const u16* __restrict__ vpT, u16* __restrict__ yb) {
  __shared__ __align__(16) u16 SB[17920];   // 35840 B -> 4 blocks/CU
  const int qt = blockIdx.x;
  const int bh = blockIdx.y;
  const int b = bh >> 4, h = bh & 15;
  const int tid = threadIdx.x;
  const int wave = tid >> 6;
  const int lane = tid & 63;
  const int fr = lane & 15;
  const int g  = lane >> 4;
  const int ko = g * 8;
  const int wq0 = qt * 64 + wave * 16;
  const int i_abs = wq0 + fr;

  const u16* prow = proj + (size_t)(b * 2048) * 5120;
  const u16* kpr = kpb + (size_t)bh * 8192;
  const u16* vptb = vpT + (size_t)bh * 8192;

  #pragma unroll
  for (int it = 0; it < 5; it++) {
    const int inst = it * 4 + wave;
    if (inst < 18) {
      const int c = inst * 64 + lane;
      const int row = c / 9;
      const int sl = c - row * 9;
      gl16(kpr + (size_t)row * 64 + (sl & 7) * 8, &SB[inst * 512]);
    }
  }
  #pragma unroll
  for (int it = 0; it < 5; it++) {
    const int inst = it * 4 + wave;
    if (inst < 17) {
      const int c = inst * 64 + lane;
      const int row = c / 17;
      const int sl = c - row * 17;
      gl16(vptb + (size_t)row * 128 + (sl & 15) * 8, &SB[9216 + inst * 512]);
    }
  }
  const sh8 bq0 = *(const sh8*)(prow + (size_t)i_abs * 5120 + h * 64 + ko);
  const sh8 bq1 = *(const sh8*)(prow + (size_t)i_abs * 5120 + h * 64 + 32 + ko);
  const int yrow = lane >> 2;
  const int yc0 = (lane & 3) * 16;
  u16* gy = yb + (size_t)(b * 2048 + wq0 + yrow) * 1024 + h * 64 + yc0;
  const us8 yold0 = *(const us8*)gy;
  const us8 yold1 = *(const us8*)(gy + 8);
  __syncthreads();   // barrier 1

  const int nf = ((wq0 + 15) >> 8) + 1;   // 1..8, wave-uniform
  f4 sc[8];
  #pragma unroll
  for (int f = 0; f < 8; f++) sc[f] = f4{0.f, 0.f, 0.f, 0.f};
  #pragma unroll
  for (int kh = 0; kh < 2; kh++) {
    const sh8 bq = kh ? bq1 : bq0;
    #pragma unroll
    for (int f = 0; f < 8; f++)
      if (f < nf) {
        sh8 ak = *(const sh8*)&SB[(f * 16 + fr) * 72 + kh * 32 + ko];
        sc[f] = __builtin_amdgcn_mfma_f32_16x16x32_bf16(ak, bq, sc[f], 0, 0, 0);
      }
  }
  float m2 = -1e30f;
  #pragma unroll
  for (int f = 0; f < 8; f++)
    #pragma unroll
    for (int r = 0; r < 4; r++) {
      const int jj = f * 16 + g * 4 + r;
      const bool ok = (jj <= 126) && (16 * jj <= i_abs);
      const float v = ok ? sc[f][r] * 0.125f : -1e30f;
      sc[f][r] = v; m2 = fmaxf(m2, v);
    }
  m2 = fmaxf(m2, __shfl_xor(m2, 16));
  m2 = fmaxf(m2, __shfl_xor(m2, 32));
  float l2 = 0.f;
  #pragma unroll
  for (int f = 0; f < 8; f++)
    #pragma unroll
    for (int r = 0; r < 4; r++) {
      const float p = __expf(sc[f][r] - m2);
      sc[f][r] = p; l2 += p;
    }
  l2 += __shfl_xor(l2, 16);
  l2 += __shfl_xor(l2, 32);
  const float inv2 = 1.f / l2;    // l2>0: block 0 allowed for every i

  __syncthreads();   // barrier 2: KC reads done; region becomes P

  u16* Pw = &SB[wave * 2176];     // [16][136]
  #pragma unroll
  for (int f = 0; f < 8; f++)
    if (f < nf)
      *(ui2*)&Pw[fr * 136 + f * 16 + g * 4] =
          pk4(sc[f][0] * inv2, sc[f][1] * inv2, sc[f][2] * inv2, sc[f][3] * inv2);
  if (nf & 1)
    *(ui2*)&Pw[fr * 136 + nf * 16 + g * 4] = ui2{0u, 0u};   // pad odd frag

  f4 yacc[4];
  #pragma unroll
  for (int ni = 0; ni < 4; ni++) yacc[ni] = f4{0.f, 0.f, 0.f, 0.f};
  const int nks = (nf + 1) >> 1;
  #pragma unroll
  for (int ks = 0; ks < 4; ks++)
    if (ks < nks) {
      sh8 pa = *(const sh8*)&Pw[fr * 136 + ks * 32 + ko];
      #pragma unroll
      for (int ni = 0; ni < 4; ni++) {
        sh8 vb = *(const sh8*)&SB[9216 + (ni * 16 + fr) * 136 + ks * 32 + ko];
        yacc[ni] = __builtin_amdgcn_mfma_f32_16x16x32_bf16(pa, vb, yacc[ni], 0, 0, 0);
      }
    }

  #pragma unroll
  for (int ni = 0; ni < 4; ni++)
    #pragma unroll
    for (int r = 0; r < 4; r++)
      Pw[(4 * g + r) * 72 + ni * 16 + fr] = f2bf(yacc[ni][r]);
  {
    const us8 yc = *(const us8*)&Pw[yrow * 72 + yc0];
    const us8 yc2 = *(const us8*)&Pw[yrow * 72 + yc0 + 8];
    us8 o0, o1;
    #pragma unroll
    for (int jj = 0; jj < 8; jj++) {
      o0[jj] = f2bf(bf2f(yold0[jj]) + bf2f(yc[jj]));
      o1[jj] = f2bf(bf2f(yold1[jj]) + bf2f(yc2[jj]));
    }
    *(us8*)gy       = o0;
    *(us8*)(gy + 8) = o1;
  }
}

extern "C" void kernel_launch(void* const* d_in, const int* in_sizes, int n_in,
                              void* d_out, int out_size, void* d_ws, size_t ws_size,
                              hipStream_t stream) {
  const float* x  = (const float*)d_in[0];
  const float* Wq = (const float*)d_in[1];
  const float* Wl = (const float*)d_in[2];
  const float* Wc = (const float*)d_in[3];
  const float* Wo = (const float*)d_in[4];
  // dkc/dvc unused: n_def == 0 at T=2048.
  float* out = (float*)d_out;
  char* ws = (char*)d_ws;
  // workspace (72.4 MB): vlT aliases xb (xb dead after gemm1)
  u16* xb   = (u16*)(ws);                       //  8 MB  x bf16 [4096][1024]
  u16* vlT  = (u16*)(ws);                       //  8 MB  vl^T bf16 [32][64][2048] (after gemm1)
  u16* Wt   = (u16*)(ws + 8388608);             // 12 MB  weights^T bf16 [6144][1024]
  u16* proj = (u16*)(ws + 20971520);            // 40 MB  [4096][5120] q|kl|vl|kc|vc
  u16* kpb  = (u16*)(ws + 62914560);            // 512 KB pooled K bf16 [32][128][64]
  u16* vpT  = (u16*)(ws + 63438848);            // 512 KB pooled V^T bf16 [32][64][128]
  u16* yb   = (u16*)(ws + 63963136);            //  8 MB  y bf16 [4096][1024]

  k_prep<<<3584, 256, 0, stream>>>(x, Wq, Wl, Wc, Wo, xb, Wt);
  k_gemm3s<<<640, 512, 0, stream>>>(xb, Wt, proj, 4096, 5120, 1024);
  k_poolvt<<<dim3(64, 32), 256, 0, stream>>>(proj, kpb, vpT, vlT);
  k_attn_local<<<dim3(32, 32), 256, 0, stream>>>(proj, vlT, yb);
  k_attn_comp<<<dim3(32, 32), 256, 0, stream>>>(proj, kpb, vpT, yb);
  k_gemm_db<false><<<dim3(8, 32), 256, 0, stream>>>(yb, Wt + (size_t)5120 * 1024, out, 4096, 1024, 1024);
}

// Round 10
// 133.151 us; speedup vs baseline: 1.2812x; 1.0605x over previous
//
#include <hip/hip_runtime.h>

typedef unsigned short u16;
typedef unsigned int u32;
typedef __attribute__((ext_vector_type(8))) short sh8;           // 8 bf16 (4 VGPR)
typedef __attribute__((ext_vector_type(8))) unsigned short us8;
typedef __attribute__((ext_vector_type(2))) unsigned int ui2;
typedef __attribute__((ext_vector_type(4))) float f4;

__device__ __forceinline__ float bf2f(u16 u) {
  union { unsigned u; float f; } v; v.u = ((unsigned)u) << 16; return v.f;
}
__device__ __forceinline__ u16 f2bf(float f) {
  union { float f; unsigned u; } v; v.f = f;
  unsigned r = v.u + 0x7fffu + ((v.u >> 16) & 1u);   // RNE, inputs finite
  return (u16)(r >> 16);
}
// pack 4 f32 -> 4 bf16 (RNE) in 2 insts
__device__ __forceinline__ ui2 pk4(float a, float b, float c, float d) {
  u32 lo, hi;
  asm("v_cvt_pk_bf16_f32 %0, %1, %2" : "=v"(lo) : "v"(a), "v"(b));
  asm("v_cvt_pk_bf16_f32 %0, %1, %2" : "=v"(hi) : "v"(c), "v"(d));
  ui2 r; r[0] = lo; r[1] = hi; return r;
}
// async global->LDS, 16B per lane; dest = wave-uniform base + lane*16
__device__ __forceinline__ void gl16(const void* g, void* l) {
  __builtin_amdgcn_global_load_lds(
      (const __attribute__((address_space(1))) unsigned int*)g,
      (__attribute__((address_space(3))) unsigned int*)l, 16, 0, 0);
}

// ------- fused: f32->bf16 cvt (bx<2048) | weight concat+transpose (bx>=2048) -------
__global__ __launch_bounds__(256)
void k_prep(const float* __restrict__ x, const float* __restrict__ Wq,
            const float* __restrict__ Wl, const float* __restrict__ Wc,
            const float* __restrict__ Wo, u16* __restrict__ xb,
            u16* __restrict__ Wt) {
  __shared__ u16 tile[64][65];
  const int bx = blockIdx.x;
  const int t = threadIdx.x;
  if (bx < 2048) {
    const int idx = bx * 256 + t;            // < 524288 = 4194304/8
    const f4* p = (const f4*)x + (size_t)idx * 2;
    f4 a = p[0], b = p[1];
    us8 o;
    o[0] = f2bf(a[0]); o[1] = f2bf(a[1]); o[2] = f2bf(a[2]); o[3] = f2bf(a[3]);
    o[4] = f2bf(b[0]); o[5] = f2bf(b[1]); o[6] = f2bf(b[2]); o[7] = f2bf(b[3]);
    ((us8*)xb)[idx] = o;
    return;
  }
  const int id = bx - 2048;                  // 0..1535
  const int n0 = (id % 96) * 64;
  const int k0 = (id / 96) * 64;
  const float* src; int ld, col0;
  if (n0 < 1024)      { src = Wq; ld = 1024; col0 = n0; }
  else if (n0 < 3072) { src = Wl; ld = 2048; col0 = n0 - 1024; }
  else if (n0 < 5120) { src = Wc; ld = 2048; col0 = n0 - 3072; }
  else                { src = Wo; ld = 1024; col0 = n0 - 5120; }
  const int r = t >> 2;          // 0..63
  const int c0 = (t & 3) * 16;   // 0,16,32,48
  const f4* sp = (const f4*)(src + (size_t)(k0 + r) * ld + col0 + c0);
  const f4 va = sp[0], vb = sp[1], vc = sp[2], vd = sp[3];
  #pragma unroll
  for (int j = 0; j < 4; j++) {
    tile[r][c0 + j]      = f2bf(va[j]);
    tile[r][c0 + 4 + j]  = f2bf(vb[j]);
    tile[r][c0 + 8 + j]  = f2bf(vc[j]);
    tile[r][c0 + 12 + j] = f2bf(vd[j]);
  }
  __syncthreads();
  us8 o0, o1;
  #pragma unroll
  for (int j = 0; j < 8; j++) { o0[j] = tile[c0 + j][r]; o1[j] = tile[c0 + 8 + j][r]; }
  u16* op = Wt + (size_t)(n0 + r) * 1024 + k0 + c0;
  *(us8*)op       = o0;
  *(us8*)(op + 8) = o1;
}

// ======= gemm1: BK=32 3-slot counted-vmcnt pipeline, 128x128, 3 blocks/CU =======
// A[M][K] * Bt[N][K]^T -> C[M][N] bf16. 4 waves (2x2), acc 4x4.
// LDS: 3 slots x (A[128][32] + B[128][32]) = 48 KB -> 3 blocks/CU (12 waves).
// Iter kt: STAGE(kt+2) [4 gl_lds/wave] -> 8 ds_read + 16 MFMA on tile kt ->
// vmcnt(4) (retires kt+1, issued TWO iterations earlier => pre-satisfied;
// never 0 until tail) -> raw s_barrier. Slot (kt+2)%3's last reader = kt-1,
// closed >=1 barrier earlier => race-free (gemm3s-verified pattern).
// Bank spread: read slot cs=(g+(row>>1))&3 -> 8 (parity,cs)-slots x 4 banks
// (r8-equivalent distribution, measured 0 conflicts); source pre-permuted
// with inverse map cg=(cs-(row>>1))&3 (rule #21).
__global__ __launch_bounds__(256)
void k_gemm32(const u16* __restrict__ A, const u16* __restrict__ Bt,
              u16* __restrict__ C, int M, int N, int K) {
  constexpr int TSZ = 8192;                  // u16 per slot: A 4096 | B 4096
  __shared__ __align__(16) u16 LB[3 * TSZ];  // 49,152 B
  const int bm0 = blockIdx.y * 128;
  const int bn0 = blockIdx.x * 128;
  const int tid = threadIdx.x;
  const int wave = tid >> 6;
  const int lane = tid & 63;
  const int fr = lane & 15;
  const int g  = lane >> 4;
  const int wr = wave >> 1, wc = wave & 1;
  const int KT = K >> 5;
  f4 acc[4][4] = {};

  auto STAGE = [&](int t) {
    const int s = t - (t / 3) * 3;
    const size_t kofs = (size_t)t << 5;
    #pragma unroll
    for (int j = 0; j < 2; j++) {
      const int kbase = (wave * 2 + j) * 64;   // wave-uniform chunk base
      const int gidx = kbase + lane;           // 0..511
      const int row = gidx >> 2;
      const int cs = gidx & 3;                 // dest slot within row
      const int cg = (cs - (row >> 1)) & 3;    // global chunk it must hold
      gl16(A  + (size_t)(bm0 + row) * K + kofs + cg * 8, &LB[s * TSZ + kbase * 8]);
      gl16(Bt + (size_t)(bn0 + row) * K + kofs + cg * 8, &LB[s * TSZ + 4096 + kbase * 8]);
    }
  };

  STAGE(0); STAGE(1);
  __builtin_amdgcn_sched_barrier(0);
  asm volatile("s_waitcnt vmcnt(4)" ::: "memory");   // tile 0 resident
  __builtin_amdgcn_s_barrier();
  __builtin_amdgcn_sched_barrier(0);

  for (int kt = 0; kt < KT; kt++) {
    const int s = kt - (kt / 3) * 3;
    const bool pf = (kt + 2) < KT;
    if (pf) STAGE(kt + 2);
    __builtin_amdgcn_sched_barrier(0);            // issue stage before compute
    const u16* As = &LB[s * TSZ];
    const u16* Bs = &LB[s * TSZ + 4096];
    sh8 af[4], bfv[4];
    #pragma unroll
    for (int mi = 0; mi < 4; mi++) {
      const int row = wr * 64 + mi * 16 + fr;
      const int cs = (g + (row >> 1)) & 3;
      af[mi] = *(const sh8*)&As[row * 32 + cs * 8];
    }
    #pragma unroll
    for (int ni = 0; ni < 4; ni++) {
      const int row = wc * 64 + ni * 16 + fr;
      const int cs = (g + (row >> 1)) & 3;
      bfv[ni] = *(const sh8*)&Bs[row * 32 + cs * 8];
    }
    #pragma unroll
    for (int mi = 0; mi < 4; mi++)
      #pragma unroll
      for (int ni = 0; ni < 4; ni++)
        acc[mi][ni] = __builtin_amdgcn_mfma_f32_16x16x32_bf16(af[mi], bfv[ni], acc[mi][ni], 0, 0, 0);
    __builtin_amdgcn_sched_barrier(0);
    if (pf) asm volatile("s_waitcnt vmcnt(4)" ::: "memory");   // retire kt+1
    else    asm volatile("s_waitcnt vmcnt(0)" ::: "memory");   // tail drain
    __builtin_amdgcn_s_barrier();
    __builtin_amdgcn_sched_barrier(0);
  }

  const int rb = bm0 + wr * 64 + g * 4;
  const int cb = bn0 + wc * 64 + fr;
  #pragma unroll
  for (int mi = 0; mi < 4; mi++)
    #pragma unroll
    for (int ni = 0; ni < 4; ni++)
      #pragma unroll
      for (int r = 0; r < 4; r++)
        C[(size_t)(rb + mi * 16 + r) * N + cb + ni * 16] = f2bf(acc[mi][ni][r]);
}

// ======= gemm2: dbuf gl_lds MFMA GEMM (r8-verified), templated output =======
template<bool OUT_BF16>
__global__ __launch_bounds__(256)
void k_gemm_db(const u16* __restrict__ A, const u16* __restrict__ Bt,
               void* __restrict__ Cout, int M, int N, int K) {
  __shared__ __align__(16) u16 LB[2][2][8192];   // [buf][A/B][128*64]
  const int bm0 = blockIdx.y * 128;
  const int bn0 = blockIdx.x * 128;
  const int tid = threadIdx.x;
  const int wave = tid >> 6;
  const int lane = tid & 63;
  const int fr = lane & 15;
  const int g  = lane >> 4;
  const int wr = wave >> 1, wc = wave & 1;
  const int srow = lane >> 3;
  const int schunk = (lane & 7) ^ (srow & 7);
  const u16* Asrc = A  + (size_t)(bm0 + wave * 32 + srow) * K + schunk * 8;
  const u16* Bsrc = Bt + (size_t)(bn0 + wave * 32 + srow) * K + schunk * 8;
  f4 acc[4][4] = {};
  const int KT = K >> 6;

  #pragma unroll
  for (int i = 0; i < 4; i++) {
    gl16(Asrc + (size_t)(i * 8) * K, &LB[0][0][(wave * 32 + i * 8) * 64]);
    gl16(Bsrc + (size_t)(i * 8) * K, &LB[0][1][(wave * 32 + i * 8) * 64]);
  }
  __syncthreads();

  int cur = 0;
  for (int kt = 0; kt < KT; kt++) {
    if (kt + 1 < KT) {
      const size_t go = (size_t)(kt + 1) * 64;
      #pragma unroll
      for (int i = 0; i < 4; i++) {
        gl16(Asrc + (size_t)(i * 8) * K + go, &LB[cur ^ 1][0][(wave * 32 + i * 8) * 64]);
        gl16(Bsrc + (size_t)(i * 8) * K + go, &LB[cur ^ 1][1][(wave * 32 + i * 8) * 64]);
      }
    }
    __builtin_amdgcn_sched_barrier(0);
    const u16* As = &LB[cur][0][0];
    const u16* Bs = &LB[cur][1][0];
    #pragma unroll
    for (int kh = 0; kh < 2; kh++) {
      sh8 af[4], bfv[4];
      const int ch = ((kh * 4 + g) ^ (fr & 7)) * 8;
      #pragma unroll
      for (int mi = 0; mi < 4; mi++)
        af[mi] = *(const sh8*)&As[(wr * 64 + mi * 16 + fr) * 64 + ch];
      #pragma unroll
      for (int ni = 0; ni < 4; ni++)
        bfv[ni] = *(const sh8*)&Bs[(wc * 64 + ni * 16 + fr) * 64 + ch];
      #pragma unroll
      for (int mi = 0; mi < 4; mi++)
        #pragma unroll
        for (int ni = 0; ni < 4; ni++)
          acc[mi][ni] = __builtin_amdgcn_mfma_f32_16x16x32_bf16(af[mi], bfv[ni], acc[mi][ni], 0, 0, 0);
    }
    __syncthreads();
    cur ^= 1;
  }

  const int rbase = bm0 + wr * 64 + g * 4;
  const int cbase = bn0 + wc * 64 + fr;
  #pragma unroll
  for (int mi = 0; mi < 4; mi++)
    #pragma unroll
    for (int ni = 0; ni < 4; ni++)
      #pragma unroll
      for (int r = 0; r < 4; r++) {
        const size_t off = (size_t)(rbase + mi * 16 + r) * N + (cbase + ni * 16);
        if constexpr (OUT_BF16) ((u16*)Cout)[off] = f2bf(acc[mi][ni][r]);
        else                    ((float*)Cout)[off] = acc[mi][ni][r];
      }
}

// ------- fused: mean-pool (bx<32, 4 windows/block) | vl transpose (bx>=32) -------
__global__ __launch_bounds__(256)
void k_poolvt(const u16* __restrict__ proj, u16* __restrict__ kpb,
              u16* __restrict__ vpT, u16* __restrict__ vlT) {
  __shared__ u16 tile[64][72];
  const int bx = blockIdx.x;
  const int bh = blockIdx.y;
  const int b = bh >> 4, h = bh & 15;
  const int t = threadIdx.x;
  if (bx < 32) {
    const int j = bx * 4 + (t >> 6);   // 0..127 (127 = zero pad)
    const int d = t & 63;
    u16 kout = 0, vout = 0;
    if (j < 127) {
      const size_t base = (size_t)(b * 2048 + j * 16) * 5120;
      const size_t kcol = 3072 + h * 64 + d;
      const size_t vcol = 4096 + h * 64 + d;
      float ks = 0.f, vs = 0.f;
      #pragma unroll 4
      for (int r = 0; r < 32; r++) {
        const size_t off = base + (size_t)r * 5120;
        ks += bf2f(proj[off + kcol]);
        vs += bf2f(proj[off + vcol]);
      }
      kout = f2bf(ks * (1.f / 32.f));
      vout = f2bf(vs * (1.f / 32.f));
    }
    kpb[((size_t)bh * 128 + j) * 64 + d] = kout;
    vpT[((size_t)bh * 64 + d) * 128 + j] = vout;
    return;
  }
  const int tt = bx - 32;              // 0..31 token tile
  const int r = t >> 2;                // 0..63
  const int c0 = (t & 3) * 16;
  const u16* sp = proj + (size_t)(b * 2048 + tt * 64 + r) * 5120 + 2048 + h * 64 + c0;
  us8 v0 = *(const us8*)sp;
  us8 v1 = *(const us8*)(sp + 8);
  #pragma unroll
  for (int jj = 0; jj < 8; jj++) { tile[r][c0 + jj] = v0[jj]; tile[r][c0 + 8 + jj] = v1[jj]; }
  __syncthreads();
  u16* op = vlT + ((size_t)bh * 64 + r) * 2048 + tt * 64 + c0;
  #pragma unroll
  for (int jj = 0; jj < 16; jj++) op[jj] = tile[c0 + jj][r];
}

// -------- attention LOCAL phase: writes y_local (pre-normalized) to yb --------
__global__ __launch_bounds__(256)
void k_attn_local(const u16* __restrict__ proj, const u16* __restrict__ vlT,
                  u16* __restrict__ yb) {
  __shared__ __align__(16) u16 SB[26688];   // 53376 B -> 3 blocks/CU
  const int qt = blockIdx.x;          // 0..31
  const int bh = blockIdx.y;          // 0..31
  const int b = bh >> 4, h = bh & 15;
  const int tid = threadIdx.x;
  const int wave = tid >> 6;
  const int lane = tid & 63;
  const int fr = lane & 15;
  const int g  = lane >> 4;
  const int ko = g * 8;
  const int q0 = qt * 64;
  const int wq0 = q0 + wave * 16;
  const int i_abs = wq0 + fr;

  const u16* prow = proj + (size_t)(b * 2048) * 5120;
  const u16* klb = prow + 1024 + h * 64;
  const u16* vltb = vlT + (size_t)bh * 64 * 2048;

  #pragma unroll
  for (int it = 0; it < 7; it++) {
    const int inst = it * 4 + wave;
    if (inst < 27) {
      const int c = inst * 64 + lane;
      const int row = c / 9;
      const int sl = c - row * 9;
      int jg = q0 - 128 + row; if (jg < 0) jg = 0;
      gl16(klb + (size_t)jg * 5120 + (sl & 7) * 8, &SB[inst * 512]);
    }
  }
  #pragma unroll
  for (int it = 0; it < 7; it++) {
    const int inst = it * 4 + wave;
    if (inst < 25) {
      const int c = inst * 64 + lane;
      const int row = c / 25;
      const int sl = c - row * 25;
      int tc = q0 - 128 + (sl < 24 ? sl : 0) * 8; if (tc < 0) tc = 0;
      gl16(vltb + (size_t)row * 2048 + tc, &SB[13824 + inst * 512]);
    }
  }
  const sh8 bq0 = *(const sh8*)(prow + (size_t)i_abs * 5120 + h * 64 + ko);
  const sh8 bq1 = *(const sh8*)(prow + (size_t)i_abs * 5120 + h * 64 + 32 + ko);
  __syncthreads();   // barrier 1: stages resident

  f4 st[9];
  #pragma unroll
  for (int f = 0; f < 9; f++) st[f] = f4{0.f, 0.f, 0.f, 0.f};
  #pragma unroll
  for (int kh = 0; kh < 2; kh++) {
    const sh8 bq = kh ? bq1 : bq0;
    #pragma unroll
    for (int f = 0; f < 9; f++) {
      sh8 ak = *(const sh8*)&SB[(wave * 16 + f * 16 + fr) * 72 + kh * 32 + ko];
      st[f] = __builtin_amdgcn_mfma_f32_16x16x32_bf16(ak, bq, st[f], 0, 0, 0);
    }
  }
  const int klo = 128 - wq0;
  float m = -1e30f;
  #pragma unroll
  for (int f = 0; f < 9; f++)
    #pragma unroll
    for (int r = 0; r < 4; r++) {
      const int kk = f * 16 + g * 4 + r;
      const bool ok = (kk > fr) && (kk <= fr + 128) && (kk >= klo);
      const float v = ok ? st[f][r] * 0.125f : -1e30f;
      st[f][r] = v; m = fmaxf(m, v);
    }
  m = fmaxf(m, __shfl_xor(m, 16));
  m = fmaxf(m, __shfl_xor(m, 32));
  float l = 0.f;
  #pragma unroll
  for (int f = 0; f < 9; f++)
    #pragma unroll
    for (int r = 0; r < 4; r++) {
      const float p = __expf(st[f][r] - m);
      st[f][r] = p; l += p;
    }
  l += __shfl_xor(l, 16);
  l += __shfl_xor(l, 32);
  const float inv = 1.f / l;      // l>0: key j=i always allowed

  __syncthreads();   // barrier 2: KL reads done; region becomes P

  u16* Pw = &SB[wave * 2688];     // [16][168]
  #pragma unroll
  for (int f = 0; f < 9; f++)
    *(ui2*)&Pw[fr * 168 + f * 16 + g * 4] =
        pk4(st[f][0] * inv, st[f][1] * inv, st[f][2] * inv, st[f][3] * inv);
  *(ui2*)&Pw[fr * 168 + 144 + g * 4] = ui2{0u, 0u};   // zero pad kk [144,160)

  f4 yacc[4];
  #pragma unroll
  for (int ni = 0; ni < 4; ni++) yacc[ni] = f4{0.f, 0.f, 0.f, 0.f};
  #pragma unroll
  for (int ks = 0; ks < 5; ks++) {
    sh8 pa = *(const sh8*)&Pw[fr * 168 + ks * 32 + ko];
    const int col = wave * 16 + ks * 32 + ko;          // < 208, pad-safe
    #pragma unroll
    for (int ni = 0; ni < 4; ni++) {
      sh8 vb = *(const sh8*)&SB[13824 + (ni * 16 + fr) * 200 + col];
      yacc[ni] = __builtin_amdgcn_mfma_f32_16x16x32_bf16(pa, vb, yacc[ni], 0, 0, 0);
    }
  }

  #pragma unroll
  for (int ni = 0; ni < 4; ni++)
    #pragma unroll
    for (int r = 0; r < 4; r++)
      Pw[(4 * g + r) * 72 + ni * 16 + fr] = f2bf(yacc[ni][r]);
  {
    const int row = lane >> 2;
    const int c0 = (lane & 3) * 16;
    u16* gy = yb + (size_t)(b * 2048 + wq0 + row) * 1024 + h * 64 + c0;
    *(us8*)gy       = *(const us8*)&Pw[row * 72 + c0];
    *(us8*)(gy + 8) = *(const us8*)&Pw[row * 72 + c0 + 8];
  }
}

// -------- attention COMPRESSED phase: yb += y_comp (runs after local) --------
__global__ __launch_bounds__(256)
void k_attn_comp(const u16* __restrict__ proj, const u16* __restrict__ kpb,
                 const u16* __restrict__ vpT, u16* __restrict__ yb) {
  __shared__ __align__(16) u16 SB[17920];   // 35840 B -> 4 blocks/CU
  const int qt = blockIdx.x;
  const int bh = blockIdx.y;
  const int b = bh >> 4, h = bh & 15;
  const int tid = threadIdx.x;
  const int wave = tid >> 6;
  const int lane = tid & 63;
  const int fr = lane & 15;
  const int g  = lane >> 4;
  const int ko = g * 8;
  const int wq0 = qt * 64 + wave * 16;
  const int i_abs = wq0 + fr;

  const u16* prow = proj + (size_t)(b * 2048) * 5120;
  const u16* kpr = kpb + (size_t)bh * 8192;
  const u16* vptb = vpT + (size_t)bh * 8192;

  #pragma unroll
  for (int it = 0; it < 5; it++) {
    const int inst = it * 4 + wave;
    if (inst < 18) {
      const int c = inst * 64 + lane;
      const int row = c / 9;
      const int sl = c - row * 9;
      gl16(kpr + (size_t)row * 64 + (sl & 7) * 8, &SB[inst * 512]);
    }
  }
  #pragma unroll
  for (int it = 0; it < 5; it++) {
    const int inst = it * 4 + wave;
    if (inst < 17) {
      const int c = inst * 64 + lane;
      const int row = c / 17;
      const int sl = c - row * 17;
      gl16(vptb + (size_t)row * 128 + (sl & 15) * 8, &SB[9216 + inst * 512]);
    }
  }
  const sh8 bq0 = *(const sh8*)(prow + (size_t)i_abs * 5120 + h * 64 + ko);
  const sh8 bq1 = *(const sh8*)(prow + (size_t)i_abs * 5120 + h * 64 + 32 + ko);
  const int yrow = lane >> 2;
  const int yc0 = (lane & 3) * 16;
  u16* gy = yb + (size_t)(b * 2048 + wq0 + yrow) * 1024 + h * 64 + yc0;
  const us8 yold0 = *(const us8*)gy;
  const us8 yold1 = *(const us8*)(gy + 8);
  __syncthreads();   // barrier 1

  const int nf = ((wq0 + 15) >> 8) + 1;   // 1..8, wave-uniform
  f4 sc[8];
  #pragma unroll
  for (int f = 0; f < 8; f++) sc[f] = f4{0.f, 0.f, 0.f, 0.f};
  #pragma unroll
  for (int kh = 0; kh < 2; kh++) {
    const sh8 bq = kh ? bq1 : bq0;
    #pragma unroll
    for (int f = 0; f < 8; f++)
      if (f < nf) {
        sh8 ak = *(const sh8*)&SB[(f * 16 + fr) * 72 + kh * 32 + ko];
        sc[f] = __builtin_amdgcn_mfma_f32_16x16x32_bf16(ak, bq, sc[f], 0, 0, 0);
      }
  }
  float m2 = -1e30f;
  #pragma unroll
  for (int f = 0; f < 8; f++)
    #pragma unroll
    for (int r = 0; r < 4; r++) {
      const int jj = f * 16 + g * 4 + r;
      const bool ok = (jj <= 126) && (16 * jj <= i_abs);
      const float v = ok ? sc[f][r] * 0.125f : -1e30f;
      sc[f][r] = v; m2 = fmaxf(m2, v);
    }
  m2 = fmaxf(m2, __shfl_xor(m2, 16));
  m2 = fmaxf(m2, __shfl_xor(m2, 32));
  float l2 = 0.f;
  #pragma unroll
  for (int f = 0; f < 8; f++)
    #pragma unroll
    for (int r = 0; r < 4; r++) {
      const float p = __expf(sc[f][r] - m2);
      sc[f][r] = p; l2 += p;
    }
  l2 += __shfl_xor(l2, 16);
  l2 += __shfl_xor(l2, 32);
  const float inv2 = 1.f / l2;    // l2>0: block 0 allowed for every i

  __syncthreads();   // barrier 2: KC reads done; region becomes P

  u16* Pw = &SB[wave * 2176];     // [16][136]
  #pragma unroll
  for (int f = 0; f < 8; f++)
    if (f < nf)
      *(ui2*)&Pw[fr * 136 + f * 16 + g * 4] =
          pk4(sc[f][0] * inv2, sc[f][1] * inv2, sc[f][2] * inv2, sc[f][3] * inv2);
  if (nf & 1)
    *(ui2*)&Pw[fr * 136 + nf * 16 + g * 4] = ui2{0u, 0u};   // pad odd frag

  f4 yacc[4];
  #pragma unroll
  for (int ni = 0; ni < 4; ni++) yacc[ni] = f4{0.f, 0.f, 0.f, 0.f};
  const int nks = (nf + 1) >> 1;
  #pragma unroll
  for (int ks = 0; ks < 4; ks++)
    if (ks < nks) {
      sh8 pa = *(const sh8*)&Pw[fr * 136 + ks * 32 + ko];
      #pragma unroll
      for (int ni = 0; ni < 4; ni++) {
        sh8 vb = *(const sh8*)&SB[9216 + (ni * 16 + fr) * 136 + ks * 32 + ko];
        yacc[ni] = __builtin_amdgcn_mfma_f32_16x16x32_bf16(pa, vb, yacc[ni], 0, 0, 0);
      }
    }

  #pragma unroll
  for (int ni = 0; ni < 4; ni++)
    #pragma unroll
    for (int r = 0; r < 4; r++)
      Pw[(4 * g + r) * 72 + ni * 16 + fr] = f2bf(yacc[ni][r]);
  {
    const us8 yc = *(const us8*)&Pw[yrow * 72 + yc0];
    const us8 yc2 = *(const us8*)&Pw[yrow * 72 + yc0 + 8];
    us8 o0, o1;
    #pragma unroll
    for (int jj = 0; jj < 8; jj++) {
      o0[jj] = f2bf(bf2f(yold0[jj]) + bf2f(yc[jj]));
      o1[jj] = f2bf(bf2f(yold1[jj]) + bf2f(yc2[jj]));
    }
    *(us8*)gy       = o0;
    *(us8*)(gy + 8) = o1;
  }
}

extern "C" void kernel_launch(void* const* d_in, const int* in_sizes, int n_in,
                              void* d_out, int out_size, void* d_ws, size_t ws_size,
                              hipStream_t stream) {
  const float* x  = (const float*)d_in[0];
  const float* Wq = (const float*)d_in[1];
  const float* Wl = (const float*)d_in[2];
  const float* Wc = (const float*)d_in[3];
  const float* Wo = (const float*)d_in[4];
  // dkc/dvc unused: n_def == 0 at T=2048.
  float* out = (float*)d_out;
  char* ws = (char*)d_ws;
  // workspace (72.4 MB): vlT aliases xb (xb dead after gemm1)
  u16* xb   = (u16*)(ws);                       //  8 MB  x bf16 [4096][1024]
  u16* vlT  = (u16*)(ws);                       //  8 MB  vl^T bf16 [32][64][2048] (after gemm1)
  u16* Wt   = (u16*)(ws + 8388608);             // 12 MB  weights^T bf16 [6144][1024]
  u16* proj = (u16*)(ws + 20971520);            // 40 MB  [4096][5120] q|kl|vl|kc|vc
  u16* kpb  = (u16*)(ws + 62914560);            // 512 KB pooled K bf16 [32][128][64]
  u16* vpT  = (u16*)(ws + 63438848);            // 512 KB pooled V^T bf16 [32][64][128]
  u16* yb   = (u16*)(ws + 63963136);            //  8 MB  y bf16 [4096][1024]

  k_prep<<<3584, 256, 0, stream>>>(x, Wq, Wl, Wc, Wo, xb, Wt);
  k_gemm32<<<dim3(40, 32), 256, 0, stream>>>(xb, Wt, proj, 4096, 5120, 1024);
  k_poolvt<<<dim3(64, 32), 256, 0, stream>>>(proj, kpb, vpT, vlT);
  k_attn_local<<<dim3(32, 32), 256, 0, stream>>>(proj, vlT, yb);
  k_attn_comp<<<dim3(32, 32), 256, 0, stream>>>(proj, kpb, vpT, yb);
  k_gemm_db<false><<<dim3(8, 32), 256, 0, stream>>>(yb, Wt + (size_t)5120 * 1024, out, 4096, 1024, 1024);
}

// Round 11
// 128.246 us; speedup vs baseline: 1.3302x; 1.0382x over previous
//
#include <hip/hip_runtime.h>

typedef unsigned short u16;
typedef unsigned int u32;
typedef __attribute__((ext_vector_type(8))) short sh8;           // 8 bf16 (4 VGPR)
typedef __attribute__((ext_vector_type(8))) unsigned short us8;
typedef __attribute__((ext_vector_type(4))) unsigned short us4;
typedef __attribute__((ext_vector_type(2))) unsigned int ui2;
typedef __attribute__((ext_vector_type(4))) float f4;

__device__ __forceinline__ float bf2f(u16 u) {
  union { unsigned u; float f; } v; v.u = ((unsigned)u) << 16; return v.f;
}
__device__ __forceinline__ u16 f2bf(float f) {
  union { float f; unsigned u; } v; v.f = f;
  unsigned r = v.u + 0x7fffu + ((v.u >> 16) & 1u);   // RNE, inputs finite
  return (u16)(r >> 16);
}
// pack 4 f32 -> 4 bf16 (RNE) in 2 insts
__device__ __forceinline__ ui2 pk4(float a, float b, float c, float d) {
  u32 lo, hi;
  asm("v_cvt_pk_bf16_f32 %0, %1, %2" : "=v"(lo) : "v"(a), "v"(b));
  asm("v_cvt_pk_bf16_f32 %0, %1, %2" : "=v"(hi) : "v"(c), "v"(d));
  ui2 r; r[0] = lo; r[1] = hi; return r;
}
// async global->LDS, 16B per lane; dest = wave-uniform base + lane*16
__device__ __forceinline__ void gl16(const void* g, void* l) {
  __builtin_amdgcn_global_load_lds(
      (const __attribute__((address_space(1))) unsigned int*)g,
      (__attribute__((address_space(3))) unsigned int*)l, 16, 0, 0);
}

// ------- fused: f32->bf16 cvt (bx<2048) | weight concat+transpose (bx>=2048) -------
// Wt rows: [0,1024)=Wq | [1024,3072)=Wl | [3072,5120)=Wc | [5120,6144)=Wo
__global__ __launch_bounds__(256)
void k_prep(const float* __restrict__ x, const float* __restrict__ Wq,
            const float* __restrict__ Wl, const float* __restrict__ Wc,
            const float* __restrict__ Wo, u16* __restrict__ xb,
            u16* __restrict__ Wt) {
  __shared__ u16 tile[64][65];
  const int bx = blockIdx.x;
  const int t = threadIdx.x;
  if (bx < 2048) {
    const int idx = bx * 256 + t;            // < 524288 = 4194304/8
    const f4* p = (const f4*)x + (size_t)idx * 2;
    f4 a = p[0], b = p[1];
    us8 o;
    o[0] = f2bf(a[0]); o[1] = f2bf(a[1]); o[2] = f2bf(a[2]); o[3] = f2bf(a[3]);
    o[4] = f2bf(b[0]); o[5] = f2bf(b[1]); o[6] = f2bf(b[2]); o[7] = f2bf(b[3]);
    ((us8*)xb)[idx] = o;
    return;
  }
  const int id = bx - 2048;                  // 0..1535
  const int n0 = (id % 96) * 64;
  const int k0 = (id / 96) * 64;
  const float* src; int ld, col0;
  if (n0 < 1024)      { src = Wq; ld = 1024; col0 = n0; }
  else if (n0 < 3072) { src = Wl; ld = 2048; col0 = n0 - 1024; }
  else if (n0 < 5120) { src = Wc; ld = 2048; col0 = n0 - 3072; }
  else                { src = Wo; ld = 1024; col0 = n0 - 5120; }
  const int r = t >> 2;          // 0..63
  const int c0 = (t & 3) * 16;   // 0,16,32,48
  const f4* sp = (const f4*)(src + (size_t)(k0 + r) * ld + col0 + c0);
  const f4 va = sp[0], vb = sp[1], vc = sp[2], vd = sp[3];
  #pragma unroll
  for (int j = 0; j < 4; j++) {
    tile[r][c0 + j]      = f2bf(va[j]);
    tile[r][c0 + 4 + j]  = f2bf(vb[j]);
    tile[r][c0 + 8 + j]  = f2bf(vc[j]);
    tile[r][c0 + 12 + j] = f2bf(vd[j]);
  }
  __syncthreads();
  us8 o0, o1;
  #pragma unroll
  for (int j = 0; j < 8; j++) { o0[j] = tile[c0 + j][r]; o1[j] = tile[c0 + 8 + j][r]; }
  u16* op = Wt + (size_t)(n0 + r) * 1024 + k0 + c0;
  *(us8*)op       = o0;
  *(us8*)(op + 8) = o1;
}

// ---- pool x: xp[b*128+j][c] = mean32 xb[b*2048+j*16 .. +31][c]; rows j==127 zero ----
__global__ __launch_bounds__(256)
void k_poolx(const u16* __restrict__ xb, u16* __restrict__ xp) {
  const int row = blockIdx.x;        // 0..255 = b*128 + j
  const int b = row >> 7, j = row & 127;
  const int c0 = threadIdx.x * 4;
  if (j == 127) { *(ui2*)&xp[(size_t)row * 1024 + c0] = ui2{0u, 0u}; return; }
  const u16* src = xb + ((size_t)(b * 2048 + j * 16)) * 1024 + c0;
  float s0 = 0.f, s1 = 0.f, s2 = 0.f, s3 = 0.f;
  #pragma unroll 8
  for (int r = 0; r < 32; r++) {
    us4 v = *(const us4*)(src + (size_t)r * 1024);
    s0 += bf2f(v[0]); s1 += bf2f(v[1]); s2 += bf2f(v[2]); s3 += bf2f(v[3]);
  }
  const float inv = 1.f / 32.f;
  *(ui2*)&xp[(size_t)row * 1024 + c0] = pk4(s0 * inv, s1 * inv, s2 * inv, s3 * inv);
}

// ======= dbuf gl_lds MFMA GEMM (r8-verified), A[M][K] * Bt[N][K]^T -> C =======
// 128x128 tile, BK=64, 256 thr (4 waves 2x2), 2 LDS bufs (64KB -> 2 blocks/CU).
// Per K-tile: issue next-tile gl_lds FIRST, compute current, one __syncthreads.
// Swizzle: stage lane chunk (l&7)^(row&7); read chunk (kh*4+g)^(fr&7) -> 0 conflicts.
template<bool OUT_BF16>
__global__ __launch_bounds__(256)
void k_gemm_db(const u16* __restrict__ A, const u16* __restrict__ Bt,
               void* __restrict__ Cout, int M, int N, int K) {
  __shared__ __align__(16) u16 LB[2][2][8192];   // [buf][A/B][128*64]
  const int bm0 = blockIdx.y * 128;
  const int bn0 = blockIdx.x * 128;
  const int tid = threadIdx.x;
  const int wave = tid >> 6;
  const int lane = tid & 63;
  const int fr = lane & 15;
  const int g  = lane >> 4;
  const int wr = wave >> 1, wc = wave & 1;
  const int srow = lane >> 3;
  const int schunk = (lane & 7) ^ (srow & 7);
  const u16* Asrc = A  + (size_t)(bm0 + wave * 32 + srow) * K + schunk * 8;
  const u16* Bsrc = Bt + (size_t)(bn0 + wave * 32 + srow) * K + schunk * 8;
  f4 acc[4][4] = {};
  const int KT = K >> 6;

  #pragma unroll
  for (int i = 0; i < 4; i++) {
    gl16(Asrc + (size_t)(i * 8) * K, &LB[0][0][(wave * 32 + i * 8) * 64]);
    gl16(Bsrc + (size_t)(i * 8) * K, &LB[0][1][(wave * 32 + i * 8) * 64]);
  }
  __syncthreads();

  int cur = 0;
  for (int kt = 0; kt < KT; kt++) {
    if (kt + 1 < KT) {
      const size_t go = (size_t)(kt + 1) * 64;
      #pragma unroll
      for (int i = 0; i < 4; i++) {
        gl16(Asrc + (size_t)(i * 8) * K + go, &LB[cur ^ 1][0][(wave * 32 + i * 8) * 64]);
        gl16(Bsrc + (size_t)(i * 8) * K + go, &LB[cur ^ 1][1][(wave * 32 + i * 8) * 64]);
      }
    }
    __builtin_amdgcn_sched_barrier(0);   // keep prefetch issue ahead of compute
    const u16* As = &LB[cur][0][0];
    const u16* Bs = &LB[cur][1][0];
    #pragma unroll
    for (int kh = 0; kh < 2; kh++) {
      sh8 af[4], bfv[4];
      const int ch = ((kh * 4 + g) ^ (fr & 7)) * 8;
      #pragma unroll
      for (int mi = 0; mi < 4; mi++)
        af[mi] = *(const sh8*)&As[(wr * 64 + mi * 16 + fr) * 64 + ch];
      #pragma unroll
      for (int ni = 0; ni < 4; ni++)
        bfv[ni] = *(const sh8*)&Bs[(wc * 64 + ni * 16 + fr) * 64 + ch];
      #pragma unroll
      for (int mi = 0; mi < 4; mi++)
        #pragma unroll
        for (int ni = 0; ni < 4; ni++)
          acc[mi][ni] = __builtin_amdgcn_mfma_f32_16x16x32_bf16(af[mi], bfv[ni], acc[mi][ni], 0, 0, 0);
    }
    __syncthreads();   // drains vmcnt (prefetch landed) + lgkmcnt, fences buffers
    cur ^= 1;
  }

  const int rbase = bm0 + wr * 64 + g * 4;
  const int cbase = bn0 + wc * 64 + fr;
  #pragma unroll
  for (int mi = 0; mi < 4; mi++)
    #pragma unroll
    for (int ni = 0; ni < 4; ni++)
      #pragma unroll
      for (int r = 0; r < 4; r++) {
        const size_t off = (size_t)(rbase + mi * 16 + r) * N + (cbase + ni * 16);
        if constexpr (OUT_BF16) ((u16*)Cout)[off] = f2bf(acc[mi][ni][r]);
        else                    ((float*)Cout)[off] = acc[mi][ni][r];
      }
}

// ------- fused: C2 reorg -> kpb,vpT (bx<4) | vl transpose (bx in [4,36)) -------
// C2[256 rows=b*128+j][2048 cols = kc_pool(0..1023) | vc_pool(1024..2047)]
__global__ __launch_bounds__(256)
void k_poolvt(const u16* __restrict__ proj, const u16* __restrict__ C2,
              u16* __restrict__ kpb, u16* __restrict__ vpT, u16* __restrict__ vlT) {
  __shared__ u16 tile[64][72];
  const int bx = blockIdx.x;
  const int bh = blockIdx.y;
  const int b = bh >> 4, h = bh & 15;
  const int t = threadIdx.x;
  if (bx < 4) {
    const int d = t & 63;
    const int jj = t >> 6;             // 0..3
    #pragma unroll
    for (int j0 = 0; j0 < 8; j0++) {
      const int j = bx * 32 + jj * 8 + j0;    // 0..127 (row 127 = zeros from xp pad)
      const size_t crow = (size_t)(b * 128 + j) * 2048;
      kpb[((size_t)bh * 128 + j) * 64 + d] = C2[crow + h * 64 + d];
      vpT[((size_t)bh * 64 + d) * 128 + j] = C2[crow + 1024 + h * 64 + d];
    }
    return;
  }
  const int tt = bx - 4;               // 0..31 token tile
  const int r = t >> 2;                // 0..63
  const int c0 = (t & 3) * 16;
  const u16* sp = proj + (size_t)(b * 2048 + tt * 64 + r) * 3072 + 2048 + h * 64 + c0;
  us8 v0 = *(const us8*)sp;
  us8 v1 = *(const us8*)(sp + 8);
  #pragma unroll
  for (int jj = 0; jj < 8; jj++) { tile[r][c0 + jj] = v0[jj]; tile[r][c0 + 8 + jj] = v1[jj]; }
  __syncthreads();
  u16* op = vlT + ((size_t)bh * 64 + r) * 2048 + tt * 64 + c0;
  #pragma unroll
  for (int jj = 0; jj < 16; jj++) op[jj] = tile[c0 + jj][r];
}

// -------- attention LOCAL phase: writes y_local (pre-normalized) to yb --------
// proj layout now [4096][3072]: q(0) | kl(1024) | vl(2048)
__global__ __launch_bounds__(256)
void k_attn_local(const u16* __restrict__ proj, const u16* __restrict__ vlT,
                  u16* __restrict__ yb) {
  __shared__ __align__(16) u16 SB[26688];   // 53376 B -> 3 blocks/CU
  const int qt = blockIdx.x;          // 0..31
  const int bh = blockIdx.y;          // 0..31
  const int b = bh >> 4, h = bh & 15;
  const int tid = threadIdx.x;
  const int wave = tid >> 6;
  const int lane = tid & 63;
  const int fr = lane & 15;
  const int g  = lane >> 4;
  const int ko = g * 8;
  const int q0 = qt * 64;
  const int wq0 = q0 + wave * 16;
  const int i_abs = wq0 + fr;

  const u16* prow = proj + (size_t)(b * 2048) * 3072;
  const u16* klb = prow + 1024 + h * 64;
  const u16* vltb = vlT + (size_t)bh * 64 * 2048;

  #pragma unroll
  for (int it = 0; it < 7; it++) {
    const int inst = it * 4 + wave;
    if (inst < 27) {
      const int c = inst * 64 + lane;
      const int row = c / 9;
      const int sl = c - row * 9;
      int jg = q0 - 128 + row; if (jg < 0) jg = 0;
      gl16(klb + (size_t)jg * 3072 + (sl & 7) * 8, &SB[inst * 512]);
    }
  }
  #pragma unroll
  for (int it = 0; it < 7; it++) {
    const int inst = it * 4 + wave;
    if (inst < 25) {
      const int c = inst * 64 + lane;
      const int row = c / 25;
      const int sl = c - row * 25;
      int tc = q0 - 128 + (sl < 24 ? sl : 0) * 8; if (tc < 0) tc = 0;
      gl16(vltb + (size_t)row * 2048 + tc, &SB[13824 + inst * 512]);
    }
  }
  const sh8 bq0 = *(const sh8*)(prow + (size_t)i_abs * 3072 + h * 64 + ko);
  const sh8 bq1 = *(const sh8*)(prow + (size_t)i_abs * 3072 + h * 64 + 32 + ko);
  __syncthreads();   // barrier 1: stages resident

  f4 st[9];
  #pragma unroll
  for (int f = 0; f < 9; f++) st[f] = f4{0.f, 0.f, 0.f, 0.f};
  #pragma unroll
  for (int kh = 0; kh < 2; kh++) {
    const sh8 bq = kh ? bq1 : bq0;
    #pragma unroll
    for (int f = 0; f < 9; f++) {
      sh8 ak = *(const sh8*)&SB[(wave * 16 + f * 16 + fr) * 72 + kh * 32 + ko];
      st[f] = __builtin_amdgcn_mfma_f32_16x16x32_bf16(ak, bq, st[f], 0, 0, 0);
    }
  }
  const int klo = 128 - wq0;
  float m = -1e30f;
  #pragma unroll
  for (int f = 0; f < 9; f++)
    #pragma unroll
    for (int r = 0; r < 4; r++) {
      const int kk = f * 16 + g * 4 + r;
      const bool ok = (kk > fr) && (kk <= fr + 128) && (kk >= klo);
      const float v = ok ? st[f][r] * 0.125f : -1e30f;
      st[f][r] = v; m = fmaxf(m, v);
    }
  m = fmaxf(m, __shfl_xor(m, 16));
  m = fmaxf(m, __shfl_xor(m, 32));
  float l = 0.f;
  #pragma unroll
  for (int f = 0; f < 9; f++)
    #pragma unroll
    for (int r = 0; r < 4; r++) {
      const float p = __expf(st[f][r] - m);
      st[f][r] = p; l += p;
    }
  l += __shfl_xor(l, 16);
  l += __shfl_xor(l, 32);
  const float inv = 1.f / l;      // l>0: key j=i always allowed

  __syncthreads();   // barrier 2: KL reads done; region becomes P

  u16* Pw = &SB[wave * 2688];     // [16][168]
  #pragma unroll
  for (int f = 0; f < 9; f++)
    *(ui2*)&Pw[fr * 168 + f * 16 + g * 4] =
        pk4(st[f][0] * inv, st[f][1] * inv, st[f][2] * inv, st[f][3] * inv);
  *(ui2*)&Pw[fr * 168 + 144 + g * 4] = ui2{0u, 0u};   // zero pad kk [144,160)

  f4 yacc[4];
  #pragma unroll
  for (int ni = 0; ni < 4; ni++) yacc[ni] = f4{0.f, 0.f, 0.f, 0.f};
  #pragma unroll
  for (int ks = 0; ks < 5; ks++) {
    sh8 pa = *(const sh8*)&Pw[fr * 168 + ks * 32 + ko];
    const int col = wave * 16 + ks * 32 + ko;          // < 208, pad-safe
    #pragma unroll
    for (int ni = 0; ni < 4; ni++) {
      sh8 vb = *(const sh8*)&SB[13824 + (ni * 16 + fr) * 200 + col];
      yacc[ni] = __builtin_amdgcn_mfma_f32_16x16x32_bf16(pa, vb, yacc[ni], 0, 0, 0);
    }
  }

  #pragma unroll
  for (int ni = 0; ni < 4; ni++)
    #pragma unroll
    for (int r = 0; r < 4; r++)
      Pw[(4 * g + r) * 72 + ni * 16 + fr] = f2bf(yacc[ni][r]);
  {
    const int row = lane >> 2;
    const int c0 = (lane & 3) * 16;
    u16* gy = yb + (size_t)(b * 2048 + wq0 + row) * 1024 + h * 64 + c0;
    *(us8*)gy       = *(const us8*)&Pw[row * 72 + c0];
    *(us8*)(gy + 8) = *(const us8*)&Pw[row * 72 + c0 + 8];
  }
}

// -------- attention COMPRESSED phase: yb += y_comp (runs after local) --------
__global__ __launch_bounds__(256)
void k_attn_comp(const u16* __restrict__ proj, const u16* __restrict__ kpb,
                 const u16* __restrict__ vpT, u16* __restrict__ yb) {
  __shared__ __align__(16) u16 SB[17920];   // 35840 B -> 4 blocks/CU
  const int qt = blockIdx.x;
  const int bh = blockIdx.y;
  const int b = bh >> 4, h = bh & 15;
  const int tid = threadIdx.x;
  const int wave = tid >> 6;
  const int lane = tid & 63;
  const int fr = lane & 15;
  const int g  = lane >> 4;
  const int ko = g * 8;
  const int wq0 = qt * 64 + wave * 16;
  const int i_abs = wq0 + fr;

  const u16* prow = proj + (size_t)(b * 2048) * 3072;
  const u16* kpr = kpb + (size_t)bh * 8192;
  const u16* vptb = vpT + (size_t)bh * 8192;

  #pragma unroll
  for (int it = 0; it < 5; it++) {
    const int inst = it * 4 + wave;
    if (inst < 18) {
      const int c = inst * 64 + lane;
      const int row = c / 9;
      const int sl = c - row * 9;
      gl16(kpr + (size_t)row * 64 + (sl & 7) * 8, &SB[inst * 512]);
    }
  }
  #pragma unroll
  for (int it = 0; it < 5; it++) {
    const int inst = it * 4 + wave;
    if (inst < 17) {
      const int c = inst * 64 + lane;
      const int row = c / 17;
      const int sl = c - row * 17;
      gl16(vptb + (size_t)row * 128 + (sl & 15) * 8, &SB[9216 + inst * 512]);
    }
  }
  const sh8 bq0 = *(const sh8*)(prow + (size_t)i_abs * 3072 + h * 64 + ko);
  const sh8 bq1 = *(const sh8*)(prow + (size_t)i_abs * 3072 + h * 64 + 32 + ko);
  const int yrow = lane >> 2;
  const int yc0 = (lane & 3) * 16;
  u16* gy = yb + (size_t)(b * 2048 + wq0 + yrow) * 1024 + h * 64 + yc0;
  const us8 yold0 = *(const us8*)gy;
  const us8 yold1 = *(const us8*)(gy + 8);
  __syncthreads();   // barrier 1

  const int nf = ((wq0 + 15) >> 8) + 1;   // 1..8, wave-uniform
  f4 sc[8];
  #pragma unroll
  for (int f = 0; f < 8; f++) sc[f] = f4{0.f, 0.f, 0.f, 0.f};
  #pragma unroll
  for (int kh = 0; kh < 2; kh++) {
    const sh8 bq = kh ? bq1 : bq0;
    #pragma unroll
    for (int f = 0; f < 8; f++)
      if (f < nf) {
        sh8 ak = *(const sh8*)&SB[(f * 16 + fr) * 72 + kh * 32 + ko];
        sc[f] = __builtin_amdgcn_mfma_f32_16x16x32_bf16(ak, bq, sc[f], 0, 0, 0);
      }
  }
  float m2 = -1e30f;
  #pragma unroll
  for (int f = 0; f < 8; f++)
    #pragma unroll
    for (int r = 0; r < 4; r++) {
      const int jj = f * 16 + g * 4 + r;
      const bool ok = (jj <= 126) && (16 * jj <= i_abs);
      const float v = ok ? sc[f][r] * 0.125f : -1e30f;
      sc[f][r] = v; m2 = fmaxf(m2, v);
    }
  m2 = fmaxf(m2, __shfl_xor(m2, 16));
  m2 = fmaxf(m2, __shfl_xor(m2, 32));
  float l2 = 0.f;
  #pragma unroll
  for (int f = 0; f < 8; f++)
    #pragma unroll
    for (int r = 0; r < 4; r++) {
      const float p = __expf(sc[f][r] - m2);
      sc[f][r] = p; l2 += p;
    }
  l2 += __shfl_xor(l2, 16);
  l2 += __shfl_xor(l2, 32);
  const float inv2 = 1.f / l2;    // l2>0: block 0 allowed for every i

  __syncthreads();   // barrier 2: KC reads done; region becomes P

  u16* Pw = &SB[wave * 2176];     // [16][136]
  #pragma unroll
  for (int f = 0; f < 8; f++)
    if (f < nf)
      *(ui2*)&Pw[fr * 136 + f * 16 + g * 4] =
          pk4(sc[f][0] * inv2, sc[f][1] * inv2, sc[f][2] * inv2, sc[f][3] * inv2);
  if (nf & 1)
    *(ui2*)&Pw[fr * 136 + nf * 16 + g * 4] = ui2{0u, 0u};   // pad odd frag

  f4 yacc[4];
  #pragma unroll
  for (int ni = 0; ni < 4; ni++) yacc[ni] = f4{0.f, 0.f, 0.f, 0.f};
  const int nks = (nf + 1) >> 1;
  #pragma unroll
  for (int ks = 0; ks < 4; ks++)
    if (ks < nks) {
      sh8 pa = *(const sh8*)&Pw[fr * 136 + ks * 32 + ko];
      #pragma unroll
      for (int ni = 0; ni < 4; ni++) {
        sh8 vb = *(const sh8*)&SB[9216 + (ni * 16 + fr) * 136 + ks * 32 + ko];
        yacc[ni] = __builtin_amdgcn_mfma_f32_16x16x32_bf16(pa, vb, yacc[ni], 0, 0, 0);
      }
    }

  #pragma unroll
  for (int ni = 0; ni < 4; ni++)
    #pragma unroll
    for (int r = 0; r < 4; r++)
      Pw[(4 * g + r) * 72 + ni * 16 + fr] = f2bf(yacc[ni][r]);
  {
    const us8 yc = *(const us8*)&Pw[yrow * 72 + yc0];
    const us8 yc2 = *(const us8*)&Pw[yrow * 72 + yc0 + 8];
    us8 o0, o1;
    #pragma unroll
    for (int jj = 0; jj < 8; jj++) {
      o0[jj] = f2bf(bf2f(yold0[jj]) + bf2f(yc[jj]));
      o1[jj] = f2bf(bf2f(yold1[jj]) + bf2f(yc2[jj]));
    }
    *(us8*)gy       = o0;
    *(us8*)(gy + 8) = o1;
  }
}

extern "C" void kernel_launch(void* const* d_in, const int* in_sizes, int n_in,
                              void* d_out, int out_size, void* d_ws, size_t ws_size,
                              hipStream_t stream) {
  const float* x  = (const float*)d_in[0];
  const float* Wq = (const float*)d_in[1];
  const float* Wl = (const float*)d_in[2];
  const float* Wc = (const float*)d_in[3];
  const float* Wo = (const float*)d_in[4];
  // dkc/dvc unused: n_def == 0 at T=2048.
  float* out = (float*)d_out;
  char* ws = (char*)d_ws;
  // workspace (~57 MB): vlT aliases xb (xb dead after k_poolx)
  u16* xb   = (u16*)(ws);                       //  8 MB  x bf16 [4096][1024]
  u16* vlT  = (u16*)(ws);                       //  8 MB  vl^T bf16 [32][64][2048] (after poolx)
  u16* Wt   = (u16*)(ws + 8388608);             // 12 MB  weights^T bf16 [6144][1024]
  u16* proj = (u16*)(ws + 20971520);            // 24 MB  [4096][3072] q|kl|vl bf16
  u16* xp   = (u16*)(ws + 46137344);            // 512 KB pooled x bf16 [256][1024]
  u16* C2   = (u16*)(ws + 46661632);            //  1 MB  pooled proj bf16 [256][2048]
  u16* kpb  = (u16*)(ws + 47710208);            // 512 KB pooled K bf16 [32][128][64]
  u16* vpT  = (u16*)(ws + 48234496);            // 512 KB pooled V^T bf16 [32][64][128]
  u16* yb   = (u16*)(ws + 48758784);            //  8 MB  y bf16 [4096][1024]

  k_prep<<<3584, 256, 0, stream>>>(x, Wq, Wl, Wc, Wo, xb, Wt);
  k_gemm_db<true><<<dim3(24, 32), 256, 0, stream>>>(xb, Wt, proj, 4096, 3072, 1024);
  k_poolx<<<256, 256, 0, stream>>>(xb, xp);
  k_gemm_db<true><<<dim3(16, 2), 256, 0, stream>>>(xp, Wt + (size_t)3072 * 1024, C2, 256, 2048, 1024);
  k_poolvt<<<dim3(36, 32), 256, 0, stream>>>(proj, C2, kpb, vpT, vlT);
  k_attn_local<<<dim3(32, 32), 256, 0, stream>>>(proj, vlT, yb);
  k_attn_comp<<<dim3(32, 32), 256, 0, stream>>>(proj, kpb, vpT, yb);
  k_gemm_db<false><<<dim3(8, 32), 256, 0, stream>>>(yb, Wt + (size_t)5120 * 1024, out, 4096, 1024, 1024);
}

// Round 12
// 112.790 us; speedup vs baseline: 1.5125x; 1.1370x over previous
//
#include <hip/hip_runtime.h>

typedef unsigned short u16;
typedef unsigned int u32;
typedef __attribute__((ext_vector_type(8))) short sh8;           // 8 bf16 (4 VGPR)
typedef __attribute__((ext_vector_type(8))) unsigned short us8;
typedef __attribute__((ext_vector_type(2))) unsigned int ui2;
typedef __attribute__((ext_vector_type(4))) float f4;

__device__ __forceinline__ float bf2f(u16 u) {
  union { unsigned u; float f; } v; v.u = ((unsigned)u) << 16; return v.f;
}
__device__ __forceinline__ u16 f2bf(float f) {
  union { float f; unsigned u; } v; v.f = f;
  unsigned r = v.u + 0x7fffu + ((v.u >> 16) & 1u);   // RNE, inputs finite
  return (u16)(r >> 16);
}
// pack 4 f32 -> 4 bf16 (RNE) in 2 insts
__device__ __forceinline__ ui2 pk4(float a, float b, float c, float d) {
  u32 lo, hi;
  asm("v_cvt_pk_bf16_f32 %0, %1, %2" : "=v"(lo) : "v"(a), "v"(b));
  asm("v_cvt_pk_bf16_f32 %0, %1, %2" : "=v"(hi) : "v"(c), "v"(d));
  ui2 r; r[0] = lo; r[1] = hi; return r;
}
// async global->LDS, 16B per lane; dest = wave-uniform base + lane*16
__device__ __forceinline__ void gl16(const void* g, void* l) {
  __builtin_amdgcn_global_load_lds(
      (const __attribute__((address_space(1))) unsigned int*)g,
      (__attribute__((address_space(3))) unsigned int*)l, 16, 0, 0);
}

// ---- fused: f32->bf16 cvt (bx<2048) | weight transpose (2048..3583) | x-pool (>=3584) ----
// Wt rows: [0,1024)=Wq | [1024,3072)=Wl | [3072,5120)=Wc | [5120,6144)=Wo
__global__ __launch_bounds__(256)
void k_prep(const float* __restrict__ x, const float* __restrict__ Wq,
            const float* __restrict__ Wl, const float* __restrict__ Wc,
            const float* __restrict__ Wo, u16* __restrict__ xb,
            u16* __restrict__ Wt, u16* __restrict__ xp) {
  __shared__ u16 tile[64][65];
  const int bx = blockIdx.x;
  const int t = threadIdx.x;
  if (bx < 2048) {
    const int idx = bx * 256 + t;            // < 524288 = 4194304/8
    const f4* p = (const f4*)x + (size_t)idx * 2;
    f4 a = p[0], b = p[1];
    us8 o;
    o[0] = f2bf(a[0]); o[1] = f2bf(a[1]); o[2] = f2bf(a[2]); o[3] = f2bf(a[3]);
    o[4] = f2bf(b[0]); o[5] = f2bf(b[1]); o[6] = f2bf(b[2]); o[7] = f2bf(b[3]);
    ((us8*)xb)[idx] = o;
    return;
  }
  if (bx >= 3584) {                          // x-pool: xp[b*128+j] = mean32 x rows (f32 src)
    const int row = bx - 3584;               // 0..255
    const int b = row >> 7, j = row & 127;
    const int c0 = t * 4;
    if (j == 127) { *(ui2*)&xp[(size_t)row * 1024 + c0] = ui2{0u, 0u}; return; }
    const float* src = x + ((size_t)(b * 2048 + j * 16)) * 1024 + c0;
    float s0 = 0.f, s1 = 0.f, s2 = 0.f, s3 = 0.f;
    #pragma unroll 8
    for (int r = 0; r < 32; r++) {
      f4 v = *(const f4*)(src + (size_t)r * 1024);
      s0 += v[0]; s1 += v[1]; s2 += v[2]; s3 += v[3];
    }
    const float inv = 1.f / 32.f;
    *(ui2*)&xp[(size_t)row * 1024 + c0] = pk4(s0 * inv, s1 * inv, s2 * inv, s3 * inv);
    return;
  }
  const int id = bx - 2048;                  // 0..1535
  const int n0 = (id % 96) * 64;
  const int k0 = (id / 96) * 64;
  const float* src; int ld, col0;
  if (n0 < 1024)      { src = Wq; ld = 1024; col0 = n0; }
  else if (n0 < 3072) { src = Wl; ld = 2048; col0 = n0 - 1024; }
  else if (n0 < 5120) { src = Wc; ld = 2048; col0 = n0 - 3072; }
  else                { src = Wo; ld = 1024; col0 = n0 - 5120; }
  const int r = t >> 2;          // 0..63
  const int c0 = (t & 3) * 16;   // 0,16,32,48
  const f4* sp = (const f4*)(src + (size_t)(k0 + r) * ld + col0 + c0);
  const f4 va = sp[0], vb = sp[1], vc = sp[2], vd = sp[3];
  #pragma unroll
  for (int j = 0; j < 4; j++) {
    tile[r][c0 + j]      = f2bf(va[j]);
    tile[r][c0 + 4 + j]  = f2bf(vb[j]);
    tile[r][c0 + 8 + j]  = f2bf(vc[j]);
    tile[r][c0 + 12 + j] = f2bf(vd[j]);
  }
  __syncthreads();
  us8 o0, o1;
  #pragma unroll
  for (int j = 0; j < 8; j++) { o0[j] = tile[c0 + j][r]; o1[j] = tile[c0 + 8 + j][r]; }
  u16* op = Wt + (size_t)(n0 + r) * 1024 + k0 + c0;
  *(us8*)op       = o0;
  *(us8*)(op + 8) = o1;
}

// ======= gemm1 fused: proj (id<768) + pooled proj (id>=768), flat grid 800 =======
// dbuf gl_lds 128x128 BK=64 (r8-verified structure). K=1024 for both paths.
__global__ __launch_bounds__(256)
void k_gemm1f(const u16* __restrict__ xb, const u16* __restrict__ xp,
              const u16* __restrict__ Wt, u16* __restrict__ proj,
              u16* __restrict__ C2) {
  __shared__ __align__(16) u16 LB[2][2][8192];   // [buf][A/B][128*64]
  constexpr int K = 1024;
  const int id = blockIdx.x;
  const u16 *Ab, *Bb; u16* Cb; int bm0, bn0, Nout;
  if (id < 768) {
    bm0 = (id / 24) * 128; bn0 = (id % 24) * 128;
    Ab = xb; Bb = Wt; Cb = proj; Nout = 3072;
  } else {
    const int p = id - 768;                  // 0..31
    bm0 = (p >> 4) * 128; bn0 = (p & 15) * 128;
    Ab = xp; Bb = Wt + (size_t)3072 * 1024; Cb = C2; Nout = 2048;
  }
  const int tid = threadIdx.x;
  const int wave = tid >> 6;
  const int lane = tid & 63;
  const int fr = lane & 15;
  const int g  = lane >> 4;
  const int wr = wave >> 1, wc = wave & 1;
  const int srow = lane >> 3;
  const int schunk = (lane & 7) ^ (srow & 7);
  const u16* Asrc = Ab + (size_t)(bm0 + wave * 32 + srow) * K + schunk * 8;
  const u16* Bsrc = Bb + (size_t)(bn0 + wave * 32 + srow) * K + schunk * 8;
  f4 acc[4][4] = {};
  const int KT = K >> 6;

  #pragma unroll
  for (int i = 0; i < 4; i++) {
    gl16(Asrc + (size_t)(i * 8) * K, &LB[0][0][(wave * 32 + i * 8) * 64]);
    gl16(Bsrc + (size_t)(i * 8) * K, &LB[0][1][(wave * 32 + i * 8) * 64]);
  }
  __syncthreads();

  int cur = 0;
  for (int kt = 0; kt < KT; kt++) {
    if (kt + 1 < KT) {
      const size_t go = (size_t)(kt + 1) * 64;
      #pragma unroll
      for (int i = 0; i < 4; i++) {
        gl16(Asrc + (size_t)(i * 8) * K + go, &LB[cur ^ 1][0][(wave * 32 + i * 8) * 64]);
        gl16(Bsrc + (size_t)(i * 8) * K + go, &LB[cur ^ 1][1][(wave * 32 + i * 8) * 64]);
      }
    }
    __builtin_amdgcn_sched_barrier(0);
    const u16* As = &LB[cur][0][0];
    const u16* Bs = &LB[cur][1][0];
    #pragma unroll
    for (int kh = 0; kh < 2; kh++) {
      sh8 af[4], bfv[4];
      const int ch = ((kh * 4 + g) ^ (fr & 7)) * 8;
      #pragma unroll
      for (int mi = 0; mi < 4; mi++)
        af[mi] = *(const sh8*)&As[(wr * 64 + mi * 16 + fr) * 64 + ch];
      #pragma unroll
      for (int ni = 0; ni < 4; ni++)
        bfv[ni] = *(const sh8*)&Bs[(wc * 64 + ni * 16 + fr) * 64 + ch];
      #pragma unroll
      for (int mi = 0; mi < 4; mi++)
        #pragma unroll
        for (int ni = 0; ni < 4; ni++)
          acc[mi][ni] = __builtin_amdgcn_mfma_f32_16x16x32_bf16(af[mi], bfv[ni], acc[mi][ni], 0, 0, 0);
    }
    __syncthreads();
    cur ^= 1;
  }

  const int rbase = bm0 + wr * 64 + g * 4;
  const int cbase = bn0 + wc * 64 + fr;
  #pragma unroll
  for (int mi = 0; mi < 4; mi++)
    #pragma unroll
    for (int ni = 0; ni < 4; ni++)
      #pragma unroll
      for (int r = 0; r < 4; r++)
        Cb[(size_t)(rbase + mi * 16 + r) * Nout + cbase + ni * 16] = f2bf(acc[mi][ni][r]);
}

// ======= gemm2: dbuf gl_lds MFMA GEMM (r8-verified), f32 out =======
__global__ __launch_bounds__(256)
void k_gemm_db(const u16* __restrict__ A, const u16* __restrict__ Bt,
               float* __restrict__ Cout, int M, int N, int K) {
  __shared__ __align__(16) u16 LB[2][2][8192];   // [buf][A/B][128*64]
  const int bm0 = blockIdx.y * 128;
  const int bn0 = blockIdx.x * 128;
  const int tid = threadIdx.x;
  const int wave = tid >> 6;
  const int lane = tid & 63;
  const int fr = lane & 15;
  const int g  = lane >> 4;
  const int wr = wave >> 1, wc = wave & 1;
  const int srow = lane >> 3;
  const int schunk = (lane & 7) ^ (srow & 7);
  const u16* Asrc = A  + (size_t)(bm0 + wave * 32 + srow) * K + schunk * 8;
  const u16* Bsrc = Bt + (size_t)(bn0 + wave * 32 + srow) * K + schunk * 8;
  f4 acc[4][4] = {};
  const int KT = K >> 6;

  #pragma unroll
  for (int i = 0; i < 4; i++) {
    gl16(Asrc + (size_t)(i * 8) * K, &LB[0][0][(wave * 32 + i * 8) * 64]);
    gl16(Bsrc + (size_t)(i * 8) * K, &LB[0][1][(wave * 32 + i * 8) * 64]);
  }
  __syncthreads();

  int cur = 0;
  for (int kt = 0; kt < KT; kt++) {
    if (kt + 1 < KT) {
      const size_t go = (size_t)(kt + 1) * 64;
      #pragma unroll
      for (int i = 0; i < 4; i++) {
        gl16(Asrc + (size_t)(i * 8) * K + go, &LB[cur ^ 1][0][(wave * 32 + i * 8) * 64]);
        gl16(Bsrc + (size_t)(i * 8) * K + go, &LB[cur ^ 1][1][(wave * 32 + i * 8) * 64]);
      }
    }
    __builtin_amdgcn_sched_barrier(0);
    const u16* As = &LB[cur][0][0];
    const u16* Bs = &LB[cur][1][0];
    #pragma unroll
    for (int kh = 0; kh < 2; kh++) {
      sh8 af[4], bfv[4];
      const int ch = ((kh * 4 + g) ^ (fr & 7)) * 8;
      #pragma unroll
      for (int mi = 0; mi < 4; mi++)
        af[mi] = *(const sh8*)&As[(wr * 64 + mi * 16 + fr) * 64 + ch];
      #pragma unroll
      for (int ni = 0; ni < 4; ni++)
        bfv[ni] = *(const sh8*)&Bs[(wc * 64 + ni * 16 + fr) * 64 + ch];
      #pragma unroll
      for (int mi = 0; mi < 4; mi++)
        #pragma unroll
        for (int ni = 0; ni < 4; ni++)
          acc[mi][ni] = __builtin_amdgcn_mfma_f32_16x16x32_bf16(af[mi], bfv[ni], acc[mi][ni], 0, 0, 0);
    }
    __syncthreads();
    cur ^= 1;
  }

  const int rbase = bm0 + wr * 64 + g * 4;
  const int cbase = bn0 + wc * 64 + fr;
  #pragma unroll
  for (int mi = 0; mi < 4; mi++)
    #pragma unroll
    for (int ni = 0; ni < 4; ni++)
      #pragma unroll
      for (int r = 0; r < 4; r++)
        Cout[(size_t)(rbase + mi * 16 + r) * N + cbase + ni * 16] = acc[mi][ni][r];
}

// ------- fused: C2 reorg -> kpb,vpT (bx<4) | vl transpose (bx in [4,36)) -------
__global__ __launch_bounds__(256)
void k_poolvt(const u16* __restrict__ proj, const u16* __restrict__ C2,
              u16* __restrict__ kpb, u16* __restrict__ vpT, u16* __restrict__ vlT) {
  __shared__ u16 tile[64][72];
  const int bx = blockIdx.x;
  const int bh = blockIdx.y;
  const int b = bh >> 4, h = bh & 15;
  const int t = threadIdx.x;
  if (bx < 4) {
    const int d = t & 63;
    const int jj = t >> 6;             // 0..3
    #pragma unroll
    for (int j0 = 0; j0 < 8; j0++) {
      const int j = bx * 32 + jj * 8 + j0;    // 0..127 (row 127 = zeros from xp pad)
      const size_t crow = (size_t)(b * 128 + j) * 2048;
      kpb[((size_t)bh * 128 + j) * 64 + d] = C2[crow + h * 64 + d];
      vpT[((size_t)bh * 64 + d) * 128 + j] = C2[crow + 1024 + h * 64 + d];
    }
    return;
  }
  const int tt = bx - 4;               // 0..31 token tile
  const int r = t >> 2;                // 0..63
  const int c0 = (t & 3) * 16;
  const u16* sp = proj + (size_t)(b * 2048 + tt * 64 + r) * 3072 + 2048 + h * 64 + c0;
  us8 v0 = *(const us8*)sp;
  us8 v1 = *(const us8*)(sp + 8);
  #pragma unroll
  for (int jj = 0; jj < 8; jj++) { tile[r][c0 + jj] = v0[jj]; tile[r][c0 + 8 + jj] = v1[jj]; }
  __syncthreads();
  u16* op = vlT + ((size_t)bh * 64 + r) * 2048 + tt * 64 + c0;
  #pragma unroll
  for (int jj = 0; jj < 16; jj++) op[jj] = tile[c0 + jj][r];
}

// -------- fused attention: bx<32 local -> yb, bx>=32 comp -> yb2 (concurrent) --------
// proj layout [4096][3072]: q(0) | kl(1024) | vl(2048)
__global__ __launch_bounds__(256)
void k_attn(const u16* __restrict__ proj, const u16* __restrict__ vlT,
            const u16* __restrict__ kpb, const u16* __restrict__ vpT,
            u16* __restrict__ yb, u16* __restrict__ yb2) {
  __shared__ __align__(16) u16 SB[26688];   // 53376 B -> 3 blocks/CU
  const int bx = blockIdx.x;
  const int bh = blockIdx.y;
  const int b = bh >> 4, h = bh & 15;
  const int tid = threadIdx.x;
  const int wave = tid >> 6;
  const int lane = tid & 63;
  const int fr = lane & 15;
  const int g  = lane >> 4;
  const int ko = g * 8;
  const u16* prow = proj + (size_t)(b * 2048) * 3072;

  if (bx < 32) {
    // ================= LOCAL =================
    const int qt = bx;
    const int q0 = qt * 64;
    const int wq0 = q0 + wave * 16;
    const int i_abs = wq0 + fr;
    const u16* klb = prow + 1024 + h * 64;
    const u16* vltb = vlT + (size_t)bh * 64 * 2048;

    #pragma unroll
    for (int it = 0; it < 7; it++) {
      const int inst = it * 4 + wave;
      if (inst < 27) {
        const int c = inst * 64 + lane;
        const int row = c / 9;
        const int sl = c - row * 9;
        int jg = q0 - 128 + row; if (jg < 0) jg = 0;
        gl16(klb + (size_t)jg * 3072 + (sl & 7) * 8, &SB[inst * 512]);
      }
    }
    #pragma unroll
    for (int it = 0; it < 7; it++) {
      const int inst = it * 4 + wave;
      if (inst < 25) {
        const int c = inst * 64 + lane;
        const int row = c / 25;
        const int sl = c - row * 25;
        int tc = q0 - 128 + (sl < 24 ? sl : 0) * 8; if (tc < 0) tc = 0;
        gl16(vltb + (size_t)row * 2048 + tc, &SB[13824 + inst * 512]);
      }
    }
    const sh8 bq0 = *(const sh8*)(prow + (size_t)i_abs * 3072 + h * 64 + ko);
    const sh8 bq1 = *(const sh8*)(prow + (size_t)i_abs * 3072 + h * 64 + 32 + ko);
    __syncthreads();   // barrier 1

    f4 st[9];
    #pragma unroll
    for (int f = 0; f < 9; f++) st[f] = f4{0.f, 0.f, 0.f, 0.f};
    #pragma unroll
    for (int kh = 0; kh < 2; kh++) {
      const sh8 bq = kh ? bq1 : bq0;
      #pragma unroll
      for (int f = 0; f < 9; f++) {
        sh8 ak = *(const sh8*)&SB[(wave * 16 + f * 16 + fr) * 72 + kh * 32 + ko];
        st[f] = __builtin_amdgcn_mfma_f32_16x16x32_bf16(ak, bq, st[f], 0, 0, 0);
      }
    }
    const int klo = 128 - wq0;
    float m = -1e30f;
    #pragma unroll
    for (int f = 0; f < 9; f++)
      #pragma unroll
      for (int r = 0; r < 4; r++) {
        const int kk = f * 16 + g * 4 + r;
        const bool ok = (kk > fr) && (kk <= fr + 128) && (kk >= klo);
        const float v = ok ? st[f][r] * 0.125f : -1e30f;
        st[f][r] = v; m = fmaxf(m, v);
      }
    m = fmaxf(m, __shfl_xor(m, 16));
    m = fmaxf(m, __shfl_xor(m, 32));
    float l = 0.f;
    #pragma unroll
    for (int f = 0; f < 9; f++)
      #pragma unroll
      for (int r = 0; r < 4; r++) {
        const float p = __expf(st[f][r] - m);
        st[f][r] = p; l += p;
      }
    l += __shfl_xor(l, 16);
    l += __shfl_xor(l, 32);
    const float inv = 1.f / l;

    __syncthreads();   // barrier 2: KL region becomes P

    u16* Pw = &SB[wave * 2688];     // [16][168]
    #pragma unroll
    for (int f = 0; f < 9; f++)
      *(ui2*)&Pw[fr * 168 + f * 16 + g * 4] =
          pk4(st[f][0] * inv, st[f][1] * inv, st[f][2] * inv, st[f][3] * inv);
    *(ui2*)&Pw[fr * 168 + 144 + g * 4] = ui2{0u, 0u};

    f4 yacc[4];
    #pragma unroll
    for (int ni = 0; ni < 4; ni++) yacc[ni] = f4{0.f, 0.f, 0.f, 0.f};
    #pragma unroll
    for (int ks = 0; ks < 5; ks++) {
      sh8 pa = *(const sh8*)&Pw[fr * 168 + ks * 32 + ko];
      const int col = wave * 16 + ks * 32 + ko;
      #pragma unroll
      for (int ni = 0; ni < 4; ni++) {
        sh8 vb = *(const sh8*)&SB[13824 + (ni * 16 + fr) * 200 + col];
        yacc[ni] = __builtin_amdgcn_mfma_f32_16x16x32_bf16(pa, vb, yacc[ni], 0, 0, 0);
      }
    }

    #pragma unroll
    for (int ni = 0; ni < 4; ni++)
      #pragma unroll
      for (int r = 0; r < 4; r++)
        Pw[(4 * g + r) * 72 + ni * 16 + fr] = f2bf(yacc[ni][r]);
    const int row = lane >> 2;
    const int c0 = (lane & 3) * 16;
    u16* gy = yb + (size_t)(b * 2048 + wq0 + row) * 1024 + h * 64 + c0;
    *(us8*)gy       = *(const us8*)&Pw[row * 72 + c0];
    *(us8*)(gy + 8) = *(const us8*)&Pw[row * 72 + c0 + 8];
    return;
  }

  // ================= COMPRESSED =================
  const int qt = bx - 32;
  const int wq0 = qt * 64 + wave * 16;
  const int i_abs = wq0 + fr;
  const u16* kpr = kpb + (size_t)bh * 8192;
  const u16* vptb = vpT + (size_t)bh * 8192;

  #pragma unroll
  for (int it = 0; it < 5; it++) {
    const int inst = it * 4 + wave;
    if (inst < 18) {
      const int c = inst * 64 + lane;
      const int row = c / 9;
      const int sl = c - row * 9;
      gl16(kpr + (size_t)row * 64 + (sl & 7) * 8, &SB[inst * 512]);
    }
  }
  #pragma unroll
  for (int it = 0; it < 5; it++) {
    const int inst = it * 4 + wave;
    if (inst < 17) {
      const int c = inst * 64 + lane;
      const int row = c / 17;
      const int sl = c - row * 17;
      gl16(vptb + (size_t)row * 128 + (sl & 15) * 8, &SB[9216 + inst * 512]);
    }
  }
  const sh8 bq0 = *(const sh8*)(prow + (size_t)i_abs * 3072 + h * 64 + ko);
  const sh8 bq1 = *(const sh8*)(prow + (size_t)i_abs * 3072 + h * 64 + 32 + ko);
  __syncthreads();   // barrier 1

  const int nf = ((wq0 + 15) >> 8) + 1;   // 1..8, wave-uniform
  f4 sc[8];
  #pragma unroll
  for (int f = 0; f < 8; f++) sc[f] = f4{0.f, 0.f, 0.f, 0.f};
  #pragma unroll
  for (int kh = 0; kh < 2; kh++) {
    const sh8 bq = kh ? bq1 : bq0;
    #pragma unroll
    for (int f = 0; f < 8; f++)
      if (f < nf) {
        sh8 ak = *(const sh8*)&SB[(f * 16 + fr) * 72 + kh * 32 + ko];
        sc[f] = __builtin_amdgcn_mfma_f32_16x16x32_bf16(ak, bq, sc[f], 0, 0, 0);
      }
  }
  float m2 = -1e30f;
  #pragma unroll
  for (int f = 0; f < 8; f++)
    #pragma unroll
    for (int r = 0; r < 4; r++) {
      const int jj = f * 16 + g * 4 + r;
      const bool ok = (jj <= 126) && (16 * jj <= i_abs);
      const float v = ok ? sc[f][r] * 0.125f : -1e30f;
      sc[f][r] = v; m2 = fmaxf(m2, v);
    }
  m2 = fmaxf(m2, __shfl_xor(m2, 16));
  m2 = fmaxf(m2, __shfl_xor(m2, 32));
  float l2 = 0.f;
  #pragma unroll
  for (int f = 0; f < 8; f++)
    #pragma unroll
    for (int r = 0; r < 4; r++) {
      const float p = __expf(sc[f][r] - m2);
      sc[f][r] = p; l2 += p;
    }
  l2 += __shfl_xor(l2, 16);
  l2 += __shfl_xor(l2, 32);
  const float inv2 = 1.f / l2;

  __syncthreads();   // barrier 2: KC region becomes P

  u16* Pw = &SB[wave * 2176];     // [16][136]
  #pragma unroll
  for (int f = 0; f < 8; f++)
    if (f < nf)
      *(ui2*)&Pw[fr * 136 + f * 16 + g * 4] =
          pk4(sc[f][0] * inv2, sc[f][1] * inv2, sc[f][2] * inv2, sc[f][3] * inv2);
  if (nf & 1)
    *(ui2*)&Pw[fr * 136 + nf * 16 + g * 4] = ui2{0u, 0u};

  f4 yacc[4];
  #pragma unroll
  for (int ni = 0; ni < 4; ni++) yacc[ni] = f4{0.f, 0.f, 0.f, 0.f};
  const int nks = (nf + 1) >> 1;
  #pragma unroll
  for (int ks = 0; ks < 4; ks++)
    if (ks < nks) {
      sh8 pa = *(const sh8*)&Pw[fr * 136 + ks * 32 + ko];
      #pragma unroll
      for (int ni = 0; ni < 4; ni++) {
        sh8 vb = *(const sh8*)&SB[9216 + (ni * 16 + fr) * 136 + ks * 32 + ko];
        yacc[ni] = __builtin_amdgcn_mfma_f32_16x16x32_bf16(pa, vb, yacc[ni], 0, 0, 0);
      }
    }

  #pragma unroll
  for (int ni = 0; ni < 4; ni++)
    #pragma unroll
    for (int r = 0; r < 4; r++)
      Pw[(4 * g + r) * 72 + ni * 16 + fr] = f2bf(yacc[ni][r]);
  const int row = lane >> 2;
  const int c0 = (lane & 3) * 16;
  u16* gy = yb2 + (size_t)(b * 2048 + wq0 + row) * 1024 + h * 64 + c0;
  *(us8*)gy       = *(const us8*)&Pw[row * 72 + c0];
  *(us8*)(gy + 8) = *(const us8*)&Pw[row * 72 + c0 + 8];
}

// ---- yb += yb2 (bf16, elementwise, 8/thread) ----
__global__ __launch_bounds__(256)
void k_sum(u16* __restrict__ yb, const u16* __restrict__ yb2) {
  const int idx = blockIdx.x * 256 + threadIdx.x;   // < 524288
  us8 a = ((const us8*)yb)[idx];
  us8 b = ((const us8*)yb2)[idx];
  ui2 lo = pk4(bf2f(a[0]) + bf2f(b[0]), bf2f(a[1]) + bf2f(b[1]),
               bf2f(a[2]) + bf2f(b[2]), bf2f(a[3]) + bf2f(b[3]));
  ui2 hi = pk4(bf2f(a[4]) + bf2f(b[4]), bf2f(a[5]) + bf2f(b[5]),
               bf2f(a[6]) + bf2f(b[6]), bf2f(a[7]) + bf2f(b[7]));
  us8 o;
  o[0] = (u16)lo[0]; o[1] = (u16)(lo[0] >> 16); o[2] = (u16)lo[1]; o[3] = (u16)(lo[1] >> 16);
  o[4] = (u16)hi[0]; o[5] = (u16)(hi[0] >> 16); o[6] = (u16)hi[1]; o[7] = (u16)(hi[1] >> 16);
  ((us8*)yb)[idx] = o;
}

extern "C" void kernel_launch(void* const* d_in, const int* in_sizes, int n_in,
                              void* d_out, int out_size, void* d_ws, size_t ws_size,
                              hipStream_t stream) {
  const float* x  = (const float*)d_in[0];
  const float* Wq = (const float*)d_in[1];
  const float* Wl = (const float*)d_in[2];
  const float* Wc = (const float*)d_in[3];
  const float* Wo = (const float*)d_in[4];
  // dkc/dvc unused: n_def == 0 at T=2048.
  float* out = (float*)d_out;
  char* ws = (char*)d_ws;
  // workspace (~65.5 MB): vlT aliases xb (xb dead after gemm1f)
  u16* xb   = (u16*)(ws);                       //  8 MB  x bf16 [4096][1024]
  u16* vlT  = (u16*)(ws);                       //  8 MB  vl^T bf16 [32][64][2048] (after gemm1f)
  u16* Wt   = (u16*)(ws + 8388608);             // 12 MB  weights^T bf16 [6144][1024]
  u16* proj = (u16*)(ws + 20971520);            // 24 MB  [4096][3072] q|kl|vl bf16
  u16* xp   = (u16*)(ws + 46137344);            // 512 KB pooled x bf16 [256][1024]
  u16* C2   = (u16*)(ws + 46661632);            //  1 MB  pooled proj bf16 [256][2048]
  u16* kpb  = (u16*)(ws + 47710208);            // 512 KB pooled K bf16 [32][128][64]
  u16* vpT  = (u16*)(ws + 48234496);            // 512 KB pooled V^T bf16 [32][64][128]
  u16* yb   = (u16*)(ws + 48758784);            //  8 MB  y_local bf16 [4096][1024]
  u16* yb2  = (u16*)(ws + 57147392);            //  8 MB  y_comp  bf16 [4096][1024]

  k_prep<<<3840, 256, 0, stream>>>(x, Wq, Wl, Wc, Wo, xb, Wt, xp);
  k_gemm1f<<<800, 256, 0, stream>>>(xb, xp, Wt, proj, C2);
  k_poolvt<<<dim3(36, 32), 256, 0, stream>>>(proj, C2, kpb, vpT, vlT);
  k_attn<<<dim3(64, 32), 256, 0, stream>>>(proj, vlT, kpb, vpT, yb, yb2);
  k_sum<<<2048, 256, 0, stream>>>(yb, yb2);
  k_gemm_db<<<dim3(8, 32), 256, 0, stream>>>(yb, Wt + (size_t)5120 * 1024, out, 4096, 1024, 1024);
}